// Round 2
// baseline (89082.300 us; speedup 1.0000x reference)
//
#include <hip/hip_runtime.h>

#define NMOL 256
#define MOLS 48
#define NATOMS 12288           // NMOL*MOLS
#define NORB 192               // 4*MOLS
#define PPM 1128               // pairs per molecule = 48*47/2
#define NPAIR 288768           // NMOL*PPM
#define MATSZ 36864            // NORB*NORB
#define EVC 27.21f

// output offsets (floats)
#define F_OFF   0
#define E_OFF   9437184
#define P_OFF   9486336
#define H_OFF   18923520
#define WMAT_OFF 28360704
#define CHG_OFF 57237504
#define NCV_OFF 57249792

__device__ __forceinline__ int pairoff(int i, int j) {
    return 47 * i - (i * (i - 1)) / 2 + (j - i - 1);
}

// ---------------- per-pair: w_ss + Hcore off-diagonal blocks ----------------
__global__ void pair_kernel(
    const int* __restrict__ idxi, const int* __restrict__ idxj,
    const float* __restrict__ xij, const float* __restrict__ rij,
    const float* __restrict__ zeta_s, const float* __restrict__ zeta_p,
    const float* __restrict__ g_ss,
    const float* __restrict__ beta_s, const float* __restrict__ beta_p,
    float* __restrict__ wss, float* __restrict__ H)
{
    int pp = blockIdx.x * blockDim.x + threadIdx.x;
    if (pp >= NPAIR) return;
    int i = idxi[pp], j = idxj[pp];
    float r = rij[pp];
    float rho = 7.0f / g_ss[i] + 7.0f / g_ss[j];
    float base = 1.0f / sqrtf(r * r + rho * rho);
    float wv = EVC * base;
    wss[pp] = wv;

    float x[3] = { xij[pp * 3 + 0], xij[pp * 3 + 1], xij[pp * 3 + 2] };
    float zsi = zeta_s[i], zpi = zeta_p[i], zsj = zeta_s[j], zpj = zeta_p[j];
    float e_ss = expf(-0.5f * (zsi + zsj) * r);
    float e_sp = expf(-0.5f * (zsi + zpj) * r);
    float e_ps = expf(-0.5f * (zpi + zsj) * r);
    float e_pp = expf(-0.5f * (zpi + zpj) * r);

    float S[4][4];
    S[0][0] = e_ss;
    #pragma unroll
    for (int k = 0; k < 3; ++k) {
        S[0][1 + k] = x[k] * e_sp;
        S[1 + k][0] = -x[k] * e_ps;
        #pragma unroll
        for (int l = 0; l < 3; ++l)
            S[1 + k][1 + l] = ((k == l ? 1.0f : 0.0f) - x[k] * x[l]) * e_pp;
    }
    float boi[4] = { beta_s[i], beta_p[i], beta_p[i], beta_p[i] };
    float boj[4] = { beta_s[j], beta_p[j], beta_p[j], beta_p[j] };

    int mol = i / MOLS, ai = i % MOLS, aj = j % MOLS;
    float* Hm = H + (size_t)mol * MATSZ;
    #pragma unroll
    for (int p = 0; p < 4; ++p)
        #pragma unroll
        for (int q = 0; q < 4; ++q) {
            float v = 0.5f * (boi[p] + boj[q]) * S[p][q];
            Hm[(4 * ai + p) * NORB + 4 * aj + q] = v;
            Hm[(4 * aj + q) * NORB + 4 * ai + p] = v;
        }
}

// ---------------- w output (coalesced) ----------------
__global__ void wout_kernel(const float* __restrict__ wss, float* __restrict__ w_out)
{
    int idx = blockIdx.x * blockDim.x + threadIdx.x;
    if (idx >= NPAIR * 100) return;
    int pp = idx / 100, ab = idx % 100;
    int a = ab / 10, b = ab % 10;
    w_out[idx] = wss[pp] * (1.0f + 0.05f * (float)a) * (1.0f + 0.05f * (float)b);
}

// ---------------- per-atom: vatt gather + Hcore diagonal blocks ----------------
__global__ void atom_kernel(const int* __restrict__ Z,
    const float* __restrict__ U_ss, const float* __restrict__ U_pp,
    const float* __restrict__ wss, float* __restrict__ H)
{
    int a = blockIdx.x * blockDim.x + threadIdx.x;
    if (a >= NATOMS) return;
    int mol = a / MOLS, ai = a % MOLS;
    const float* wm = wss + mol * PPM;
    float vatt = 0.0f;
    for (int j = 0; j < MOLS; ++j) {
        if (j == ai) continue;
        int i_ = ai < j ? ai : j;
        int j_ = ai < j ? j : ai;
        float torej = (float)(Z[mol * MOLS + j] - 2);
        vatt -= torej * wm[pairoff(i_, j_)];
    }
    float u0 = U_ss[a], u1 = U_pp[a];
    float* Hm = H + (size_t)mol * MATSZ;
    #pragma unroll
    for (int p = 0; p < 4; ++p)
        #pragma unroll
        for (int q = 0; q < 4; ++q)
            Hm[(4 * ai + p) * NORB + 4 * ai + q] =
                (p == q) ? ((p == 0 ? u0 : u1) + vatt) : 0.0f;
}

// ---------------- initial density ----------------
__global__ void pinit_kernel(const int* __restrict__ Z, float* __restrict__ P)
{
    int idx = blockIdx.x * blockDim.x + threadIdx.x;
    if (idx >= NMOL * MATSZ) return;
    int mol = idx / MATSZ, rem = idx % MATSZ;
    int r = rem / NORB, c = rem % NORB;
    float v = 0.0f;
    if (r == c) v = (float)(Z[mol * MOLS + r / 4] - 2) * 0.25f;
    P[idx] = v;
}

// ---------------- Ptot (trace of diagonal density block) ----------------
__global__ void ptot_kernel(const float* __restrict__ P, float* __restrict__ Ptot)
{
    int a = blockIdx.x * blockDim.x + threadIdx.x;
    if (a >= NATOMS) return;
    int mol = a / MOLS, ai = a % MOLS;
    const float* Pm = P + (size_t)mol * MATSZ;
    float t = 0.0f;
    #pragma unroll
    for (int p = 0; p < 4; ++p) t += Pm[(4 * ai + p) * NORB + 4 * ai + p];
    Ptot[a] = t;
}

// ---------------- Fock diagonal blocks ----------------
__global__ void fockdiag_kernel(
    const float* __restrict__ P, const float* __restrict__ H, float* __restrict__ F,
    const float* __restrict__ Ptot, const float* __restrict__ wss,
    const float* __restrict__ g_ss, const float* __restrict__ g_sp,
    const float* __restrict__ g_pp, const float* __restrict__ g_p2,
    const float* __restrict__ h_sp)
{
    int a = blockIdx.x * blockDim.x + threadIdx.x;
    if (a >= NATOMS) return;
    int mol = a / MOLS, ai = a % MOLS;
    const float* wm = wss + mol * PPM;
    const float* ptm = Ptot + mol * MOLS;
    float vc = 0.0f;
    for (int j = 0; j < MOLS; ++j) {
        if (j == ai) continue;
        int i_ = ai < j ? ai : j;
        int j_ = ai < j ? j : ai;
        vc += wm[pairoff(i_, j_)] * ptm[j];
    }
    const float* Pm = P + (size_t)mol * MATSZ;
    float Pd[4][4];
    #pragma unroll
    for (int p = 0; p < 4; ++p)
        #pragma unroll
        for (int q = 0; q < 4; ++q)
            Pd[p][q] = Pm[(4 * ai + p) * NORB + 4 * ai + q];

    float Pss = Pd[0][0];
    float Pp0 = Pd[1][1], Pp1 = Pd[2][2], Pp2 = Pd[3][3];
    float Ppp = Pp0 + Pp1 + Pp2;
    float gss = g_ss[a], gsp = g_sp[a], gpp = g_pp[a], gp2 = g_p2[a], hsp = h_sp[a];
    float csp = 1.5f * hsp - 0.5f * gsp;
    float gsp_h = gsp - 0.5f * hsp;
    float fss = 0.5f * Pss * gss + Ppp * gsp_h;
    float cp = 1.25f * gp2 - 0.25f * gpp;
    float fpp0 = Pss * gsp_h + 0.5f * Pp0 * gpp + (Ppp - Pp0) * cp;
    float fpp1 = Pss * gsp_h + 0.5f * Pp1 * gpp + (Ppp - Pp1) * cp;
    float fpp2 = Pss * gsp_h + 0.5f * Pp2 * gpp + (Ppp - Pp2) * cp;
    float coff = 0.75f * gpp - 1.25f * gp2;

    float Fd[4][4];
    Fd[0][0] = fss + vc;
    Fd[1][1] = fpp0 + vc; Fd[2][2] = fpp1 + vc; Fd[3][3] = fpp2 + vc;
    #pragma unroll
    for (int k = 0; k < 3; ++k) {
        Fd[0][1 + k] = Pd[0][1 + k] * csp;
        Fd[1 + k][0] = Pd[1 + k][0] * csp;
    }
    Fd[1][2] = coff * Pd[1][2]; Fd[1][3] = coff * Pd[1][3];
    Fd[2][1] = coff * Pd[2][1]; Fd[2][3] = coff * Pd[2][3];
    Fd[3][1] = coff * Pd[3][1]; Fd[3][2] = coff * Pd[3][2];

    const float* Hm = H + (size_t)mol * MATSZ;
    float* Fm = F + (size_t)mol * MATSZ;
    #pragma unroll
    for (int p = 0; p < 4; ++p)
        #pragma unroll
        for (int q = 0; q < 4; ++q) {
            int ix = (4 * ai + p) * NORB + 4 * ai + q;
            Fm[ix] = Hm[ix] + Fd[p][q];
        }
}

// ---------------- Fock off-diagonal blocks ----------------
__global__ void fockoff_kernel(const int* __restrict__ idxi, const int* __restrict__ idxj,
    const float* __restrict__ P, const float* __restrict__ H, float* __restrict__ F,
    const float* __restrict__ wss)
{
    int pp = blockIdx.x * blockDim.x + threadIdx.x;
    if (pp >= NPAIR) return;
    int i = idxi[pp], j = idxj[pp];
    int mol = i / MOLS, ai = i % MOLS, aj = j % MOLS;
    float wv = wss[pp];
    const float* Pm = P + (size_t)mol * MATSZ;
    const float* Hm = H + (size_t)mol * MATSZ;
    float* Fm = F + (size_t)mol * MATSZ;
    #pragma unroll
    for (int p = 0; p < 4; ++p)
        #pragma unroll
        for (int q = 0; q < 4; ++q) {
            int ij = (4 * ai + p) * NORB + 4 * aj + q;
            int ji = (4 * aj + q) * NORB + 4 * ai + p;
            float f = -0.5f * wv * Pm[ij];
            Fm[ij] = Hm[ij] + f;
            Fm[ji] = Hm[ji] + f;
        }
}

// ---------------- batched eigensolver: one-sided Jacobi on sigma*I - F ----------------
// warm=1: start from B = (sigma*I - F) * Vprev  (Vprev = previous iteration's full
// orthonormal eigenbasis) -> near-orthogonal columns -> 1-3 sweeps instead of 8-16.
#define EIG_T 768
#define ESTR 196     // padded column stride in floats
#define ESTR4 49     // in float4
#define EIG_LDS (( (ESTR*NORB) + 2*NORB ) * 4 + NORB * 4)

__global__ void __launch_bounds__(EIG_T)
eigh_kernel(const float* __restrict__ Fg, const int* __restrict__ noccA,
            const float* __restrict__ Vin, float* __restrict__ Vout,
            float* __restrict__ Wout, float* __restrict__ eout,
            int mode, int warm)
{
    extern __shared__ float sm[];
    float* B = sm;                          // ESTR*NORB
    float* colv = sm + ESTR * NORB;         // NORB
    float* colv2 = colv + NORB;             // NORB
    int* slot = (int*)(colv2 + NORB);       // NORB
    __shared__ int sflag;
    __shared__ float sigma;

    const int mol = blockIdx.x;
    const int tid = threadIdx.x;
    const int team = tid >> 3, lane = tid & 7;
    const float* Fm = Fg + (size_t)mol * MATSZ;

    if (!warm) {
        // cold: load F into LDS (padded columns; symmetric so col-major == row-major)
        for (int i4 = tid; i4 < NORB * 48; i4 += EIG_T) {
            int c = i4 / 48, r4 = i4 % 48;
            ((float4*)B)[c * ESTR4 + r4] = ((const float4*)Fm)[i4];
        }
        __syncthreads();
        // Gershgorin per column from LDS
        {
            int c = tid >> 2, part = tid & 3;
            const float4* col = (const float4*)B + c * ESTR4 + part * 12;
            float s = 0.0f;
            #pragma unroll
            for (int u = 0; u < 12; ++u) {
                float4 v = col[u];
                s += fabsf(v.x) + fabsf(v.y) + fabsf(v.z) + fabsf(v.w);
            }
            s += __shfl_xor(s, 1); s += __shfl_xor(s, 2);
            if (part == 0) { float d = B[c * ESTR + c]; colv[c] = s - fabsf(d) + d; }
        }
        __syncthreads();
        if (tid < 64) {
            float m = -3.4e38f;
            for (int i = tid; i < NORB; i += 64) m = fmaxf(m, colv[i]);
            #pragma unroll
            for (int o = 32; o >= 1; o >>= 1) m = fmaxf(m, __shfl_xor(m, o));
            if (tid == 0) sigma = m + 1.0f + 1e-3f * fabsf(m);
        }
        __syncthreads();
        float sg = sigma;
        // B = sigma*I - F
        for (int i4 = tid; i4 < NORB * 48; i4 += EIG_T) {
            int c = i4 / 48, r4 = i4 % 48;
            float4* pv = (float4*)B + c * ESTR4 + r4;
            float4 v = *pv;
            v.x = -v.x; v.y = -v.y; v.z = -v.z; v.w = -v.w;
            *pv = v;
        }
        __syncthreads();
        if (tid < NORB) B[tid * ESTR + tid] += sg;
        __syncthreads();
    } else {
        // warm: load Vprev into LDS
        for (int i4 = tid; i4 < NORB * 48; i4 += EIG_T) {
            int c = i4 / 48, r4 = i4 % 48;
            ((float4*)B)[c * ESTR4 + r4] = ((const float4*)Vin)[(size_t)mol * (MATSZ / 4) + i4];
        }
        // Gershgorin per column from GLOBAL F (concurrent with V load; no dependency)
        {
            int c = tid >> 2, part = tid & 3;
            const float4* col = (const float4*)(Fm + c * NORB) + part * 12;
            float s = 0.0f;
            #pragma unroll
            for (int u = 0; u < 12; ++u) {
                float4 v = col[u];
                s += fabsf(v.x) + fabsf(v.y) + fabsf(v.z) + fabsf(v.w);
            }
            s += __shfl_xor(s, 1); s += __shfl_xor(s, 2);
            if (part == 0) { float d = Fm[c * NORB + c]; colv[c] = s - fabsf(d) + d; }
        }
        __syncthreads();
        if (tid < 64) {
            float m = -3.4e38f;
            for (int i = tid; i < NORB; i += 64) m = fmaxf(m, colv[i]);
            #pragma unroll
            for (int o = 32; o >= 1; o >>= 1) m = fmaxf(m, __shfl_xor(m, o));
            if (tid == 0) sigma = m + 1.0f + 1e-3f * fabsf(m);
        }
        __syncthreads();
        float sg = sigma;
        // B[:,j] = sg*V[:,j] - F*V[:,j], column-independent; team handles cols 2t,2t+1.
        // All 8 teams of a wave read the SAME F float4s per step -> coalesces to one
        // 128B fetch; v broadcast from LDS (same-address read, free).
        {
            int j0 = 2 * team, j1 = j0 + 1;
            float4 acc0[6], acc1[6];
            #pragma unroll
            for (int u = 0; u < 6; ++u) {
                acc0[u].x = acc0[u].y = acc0[u].z = acc0[u].w = 0.0f;
                acc1[u].x = acc1[u].y = acc1[u].z = acc1[u].w = 0.0f;
            }
            const float4* F4 = (const float4*)Fm;
            for (int k = 0; k < NORB; ++k) {
                float v0 = B[j0 * ESTR + k];
                float v1 = B[j1 * ESTR + k];
                const float4* Fk = F4 + k * 48 + lane;
                #pragma unroll
                for (int u = 0; u < 6; ++u) {
                    float4 f = Fk[8 * u];
                    acc0[u].x += f.x * v0; acc0[u].y += f.y * v0;
                    acc0[u].z += f.z * v0; acc0[u].w += f.w * v0;
                    acc1[u].x += f.x * v1; acc1[u].y += f.y * v1;
                    acc1[u].z += f.z * v1; acc1[u].w += f.w * v1;
                }
            }
            #pragma unroll
            for (int u = 0; u < 6; ++u) {
                int r4 = lane + 8 * u;
                float4* pa = (float4*)B + j0 * ESTR4 + r4;
                float4* pb = (float4*)B + j1 * ESTR4 + r4;
                float4 va = *pa, vb = *pb, oa, ob;
                oa.x = sg * va.x - acc0[u].x; oa.y = sg * va.y - acc0[u].y;
                oa.z = sg * va.z - acc0[u].z; oa.w = sg * va.w - acc0[u].w;
                ob.x = sg * vb.x - acc1[u].x; ob.y = sg * vb.y - acc1[u].y;
                ob.z = sg * vb.z - acc1[u].z; ob.w = sg * vb.w - acc1[u].w;
                *pa = oa; *pb = ob;
            }
        }
        __syncthreads();
    }
    float sg = sigma;

    if (tid == 0) sflag = 0;

    // one-sided Jacobi sweeps (tournament ordering, 96 disjoint pairs/round).
    // Interleaved lane->row mapping (r4 = lane + 8u): bank group = (4p+4l)%32,
    // 2-way per quarter-wave (free, m136). Incremental p,q (no idiv). No atomics.
    const float tol2 = 2.5e-11f;   // (5e-6 relative)^2
    const int maxsweep = warm ? 10 : 16;
    for (int sweep = 0; sweep < maxsweep; ++sweep) {
        int rot = 0;
        int p, q;
        if (team == 0) { p = NORB - 1; q = 0; }
        else           { p = team;     q = (NORB - 1) - team; }
        for (int r = 0; r < NORB - 1; ++r) {
            const float4* bp = (const float4*)B + p * ESTR4 + lane;
            const float4* bq = (const float4*)B + q * ESTR4 + lane;
            float4 xp[6], xq[6];
            #pragma unroll
            for (int u = 0; u < 6; ++u) { xp[u] = bp[8 * u]; xq[u] = bq[8 * u]; }
            float app = 0.f, aqq = 0.f, apq = 0.f;
            #pragma unroll
            for (int u = 0; u < 6; ++u) {
                app += xp[u].x * xp[u].x + xp[u].y * xp[u].y + xp[u].z * xp[u].z + xp[u].w * xp[u].w;
                aqq += xq[u].x * xq[u].x + xq[u].y * xq[u].y + xq[u].z * xq[u].z + xq[u].w * xq[u].w;
                apq += xp[u].x * xq[u].x + xp[u].y * xq[u].y + xp[u].z * xq[u].z + xp[u].w * xq[u].w;
            }
            app += __shfl_xor(app, 1); app += __shfl_xor(app, 2); app += __shfl_xor(app, 4);
            aqq += __shfl_xor(aqq, 1); aqq += __shfl_xor(aqq, 2); aqq += __shfl_xor(aqq, 4);
            apq += __shfl_xor(apq, 1); apq += __shfl_xor(apq, 2); apq += __shfl_xor(apq, 4);
            if (apq * apq > tol2 * app * aqq) {
                float zeta = (aqq - app) / (2.0f * apq);
                float t = copysignf(1.0f, zeta) / (fabsf(zeta) + sqrtf(1.0f + zeta * zeta));
                float cc = 1.0f / sqrtf(1.0f + t * t);
                float ss = t * cc;
                float4* wp = (float4*)B + p * ESTR4 + lane;
                float4* wq = (float4*)B + q * ESTR4 + lane;
                #pragma unroll
                for (int u = 0; u < 6; ++u) {
                    float4 av = xp[u], bv = xq[u], na, nb;
                    na.x = cc * av.x - ss * bv.x;  nb.x = ss * av.x + cc * bv.x;
                    na.y = cc * av.y - ss * bv.y;  nb.y = ss * av.y + cc * bv.y;
                    na.z = cc * av.z - ss * bv.z;  nb.z = ss * av.z + cc * bv.z;
                    na.w = cc * av.w - ss * bv.w;  nb.w = ss * av.w + cc * bv.w;
                    wp[8 * u] = na; wq[8 * u] = nb;
                }
                rot = 1;
            }
            __syncthreads();
            if (team != 0) p = (p == NORB - 2) ? 0 : p + 1;
            q = (q == NORB - 2) ? 0 : q + 1;
        }
        if (rot) sflag = 1;          // benign same-value race
        __syncthreads();
        int done = (sflag == 0);
        __syncthreads();
        if (tid == 0) sflag = 0;
        if (done) break;
    }

    // column norms^2
    {
        int c = tid >> 2, part = tid & 3;
        const float4* col = (const float4*)B + c * ESTR4 + part * 12;
        float s = 0.0f;
        #pragma unroll
        for (int u = 0; u < 12; ++u) {
            float4 v = col[u];
            s += v.x * v.x + v.y * v.y + v.z * v.z + v.w * v.w;
        }
        s += __shfl_xor(s, 1); s += __shfl_xor(s, 2);
        if (part == 0) colv[c] = s;
    }
    __syncthreads();

    if (mode == 0) {
        // occupied = nocc largest norms (= smallest eigenvalues of F)
        int noccm = noccA[mol];
        if (tid < NORB) {
            float nc = colv[tid];
            int rank = 0;
            for (int j2 = 0; j2 < NORB; ++j2) {
                float nj = colv[j2];
                rank += (nj > nc) || (nj == nc && j2 < tid);
            }
            slot[tid] = rank;
            colv2[tid] = rsqrtf(nc);     // 1/||b||
        }
        __syncthreads();
        float* Wm = Wout + (size_t)mol * MATSZ;
        float* Vm = Vout + (size_t)mol * MATSZ;
        for (int i4 = tid; i4 < NORB * 48; i4 += EIG_T) {
            int c = i4 / 48, r4 = i4 % 48;
            float inv = colv2[c];
            float4 v = ((float4*)B)[c * ESTR4 + r4];
            float4 nv;
            nv.x = v.x * inv; nv.y = v.y * inv; nv.z = v.z * inv; nv.w = v.w * inv;
            ((float4*)Vm)[i4] = nv;      // full basis for next warm start
            int sl = slot[c];
            if (sl < noccm) {
                float4 o;
                o.x = nv.x * 1.41421356f; o.y = nv.y * 1.41421356f;
                o.z = nv.z * 1.41421356f; o.w = nv.w * 1.41421356f;
                ((float4*)Wm)[sl * 48 + r4] = o;
            }
        }
    } else {
        // eigenvalues ascending
        if (tid < NORB) colv2[tid] = sg - sqrtf(colv[tid]);
        __syncthreads();
        if (tid < NORB) {
            float ec = colv2[tid];
            int rank = 0;
            for (int j2 = 0; j2 < NORB; ++j2) {
                float ej = colv2[j2];
                rank += (ej < ec) || (ej == ec && j2 < tid);
            }
            eout[mol * NORB + rank] = ec;
        }
    }
}

// ---------------- Pnew = W^T W, mix, err ----------------
__global__ void __launch_bounds__(256)
pmix_kernel(const float* __restrict__ W, const int* __restrict__ noccA,
            float* __restrict__ P, unsigned int* __restrict__ err, int last)
{
    int mol = blockIdx.x / 36;
    int tile = blockIdx.x % 36;
    int i0 = (tile / 6) * 32, j0 = (tile % 6) * 32;
    int K = noccA[mol];
    const float* Wm = W + (size_t)mol * MATSZ;
    __shared__ float As[32][33];
    __shared__ float Bs[32][33];
    int t = threadIdx.x;
    int ty = t >> 4, tx = t & 15;
    float acc00 = 0.f, acc01 = 0.f, acc10 = 0.f, acc11 = 0.f;
    for (int k0 = 0; k0 < K; k0 += 32) {
        for (int l = t; l < 1024; l += 256) {
            int k = l >> 5, idx = l & 31;
            bool ok = (k0 + k) < K;
            As[k][idx] = ok ? Wm[(k0 + k) * NORB + i0 + idx] : 0.0f;
            Bs[k][idx] = ok ? Wm[(k0 + k) * NORB + j0 + idx] : 0.0f;
        }
        __syncthreads();
        #pragma unroll 8
        for (int k = 0; k < 32; ++k) {
            float a0 = As[k][2 * ty], a1 = As[k][2 * ty + 1];
            float b0 = Bs[k][2 * tx], b1 = Bs[k][2 * tx + 1];
            acc00 += a0 * b0; acc01 += a0 * b1; acc10 += a1 * b0; acc11 += a1 * b1;
        }
        __syncthreads();
    }
    float* Pm = P + (size_t)mol * MATSZ;
    float lmax = 0.0f;
    int ib = i0 + 2 * ty, jb = j0 + 2 * tx;
    {
        float po, pn;
        po = Pm[ib * NORB + jb];           pn = acc00; lmax = fmaxf(lmax, fabsf(pn - po)); Pm[ib * NORB + jb] = 0.5f * (po + pn);
        po = Pm[ib * NORB + jb + 1];       pn = acc01; lmax = fmaxf(lmax, fabsf(pn - po)); Pm[ib * NORB + jb + 1] = 0.5f * (po + pn);
        po = Pm[(ib + 1) * NORB + jb];     pn = acc10; lmax = fmaxf(lmax, fabsf(pn - po)); Pm[(ib + 1) * NORB + jb] = 0.5f * (po + pn);
        po = Pm[(ib + 1) * NORB + jb + 1]; pn = acc11; lmax = fmaxf(lmax, fabsf(pn - po)); Pm[(ib + 1) * NORB + jb + 1] = 0.5f * (po + pn);
    }
    if (last) {
        #pragma unroll
        for (int o = 32; o >= 1; o >>= 1) lmax = fmaxf(lmax, __shfl_xor(lmax, o));
        __shared__ float wm4[4];
        if ((t & 63) == 0) wm4[t >> 6] = lmax;
        __syncthreads();
        if (t == 0) {
            float m = fmaxf(fmaxf(wm4[0], wm4[1]), fmaxf(wm4[2], wm4[3]));
            atomicMax(err + mol, __float_as_uint(m));
        }
    }
}

// ---------------- charge + notconverged ----------------
__global__ void finish_kernel(const int* __restrict__ Z, const float* __restrict__ P,
    const float* __restrict__ errf, float* __restrict__ chg, float* __restrict__ ncv)
{
    int a = blockIdx.x * blockDim.x + threadIdx.x;
    if (a < NATOMS) {
        int mol = a / MOLS, ai = a % MOLS;
        const float* Pm = P + (size_t)mol * MATSZ;
        float tr = 0.0f;
        #pragma unroll
        for (int p = 0; p < 4; ++p) tr += Pm[(4 * ai + p) * NORB + 4 * ai + p];
        chg[a] = (float)(Z[a] - 2) - tr;
    }
    if (a < NMOL) ncv[a] = (errf[a] > 1e-6f) ? 1.0f : 0.0f;
}

extern "C" void kernel_launch(void* const* d_in, const int* in_sizes, int n_in,
                              void* d_out, int out_size, void* d_ws, size_t ws_size,
                              hipStream_t stream)
{
    (void)in_sizes; (void)n_in; (void)out_size; (void)ws_size;

    const int*   nocc   = (const int*)d_in[3];
    const int*   Z      = (const int*)d_in[4];
    const int*   idxi   = (const int*)d_in[9];
    const int*   idxj   = (const int*)d_in[10];
    const float* xij    = (const float*)d_in[13];
    const float* rij    = (const float*)d_in[14];
    const float* zeta_s = (const float*)d_in[15];
    const float* zeta_p = (const float*)d_in[16];
    const float* U_ss   = (const float*)d_in[17];
    const float* U_pp   = (const float*)d_in[18];
    const float* g_ss   = (const float*)d_in[19];
    const float* g_sp   = (const float*)d_in[20];
    const float* g_pp   = (const float*)d_in[21];
    const float* g_p2   = (const float*)d_in[22];
    const float* h_sp   = (const float*)d_in[23];
    const float* beta_s = (const float*)d_in[24];
    const float* beta_p = (const float*)d_in[25];

    float* out     = (float*)d_out;
    float* F_out   = out + F_OFF;
    float* e_out   = out + E_OFF;
    float* P_out   = out + P_OFF;
    float* H_out   = out + H_OFF;
    float* w_out   = out + WMAT_OFF;
    float* chg_out = out + CHG_OFF;
    float* ncv_out = out + NCV_OFF;

    // V basis (37.75MB) lives in the w output region (115.5MB) during SCF;
    // wout_kernel runs LAST to restore the correct w contents.
    float* Vbuf = w_out;

    char* wsb = (char*)d_ws;
    float* Wocc = (float*)wsb;                                  // 37,748,736 B
    float* wss  = (float*)(wsb + 37748736);                     //  1,155,072 B
    float* Ptot = (float*)(wsb + 37748736 + 1155072);           //     49,152 B
    unsigned int* err = (unsigned int*)(wsb + 37748736 + 1155072 + 49152);

    hipMemsetAsync(err, 0, NMOL * sizeof(unsigned int), stream);

    hipFuncSetAttribute(reinterpret_cast<const void*>(eigh_kernel),
                        hipFuncAttributeMaxDynamicSharedMemorySize, EIG_LDS);

    pair_kernel<<<NPAIR / 256, 256, 0, stream>>>(idxi, idxj, xij, rij, zeta_s, zeta_p,
                                                 g_ss, beta_s, beta_p, wss, H_out);
    atom_kernel<<<NATOMS / 256, 256, 0, stream>>>(Z, U_ss, U_pp, wss, H_out);
    pinit_kernel<<<(NMOL * MATSZ) / 256, 256, 0, stream>>>(Z, P_out);

    for (int it = 0; it < 9; ++it) {
        ptot_kernel<<<NATOMS / 256, 256, 0, stream>>>(P_out, Ptot);
        fockdiag_kernel<<<NATOMS / 256, 256, 0, stream>>>(P_out, H_out, F_out, Ptot, wss,
                                                          g_ss, g_sp, g_pp, g_p2, h_sp);
        fockoff_kernel<<<NPAIR / 256, 256, 0, stream>>>(idxi, idxj, P_out, H_out, F_out, wss);
        if (it < 8) {
            eigh_kernel<<<NMOL, EIG_T, EIG_LDS, stream>>>(F_out, nocc, Vbuf, Vbuf,
                                                          Wocc, e_out, 0, it > 0 ? 1 : 0);
            pmix_kernel<<<NMOL * 36, 256, 0, stream>>>(Wocc, nocc, P_out, err, (it == 7) ? 1 : 0);
        } else {
            eigh_kernel<<<NMOL, EIG_T, EIG_LDS, stream>>>(F_out, nocc, Vbuf, Vbuf,
                                                          Wocc, e_out, 1, 1);
        }
    }
    finish_kernel<<<NATOMS / 256, 256, 0, stream>>>(Z, P_out, (const float*)err, chg_out, ncv_out);
    wout_kernel<<<(NPAIR * 100) / 256, 256, 0, stream>>>(wss, w_out);
}

// Round 4
// 66999.713 us; speedup vs baseline: 1.3296x; 1.3296x over previous
//
#include <hip/hip_runtime.h>

#define NMOL 256
#define MOLS 48
#define NATOMS 12288           // NMOL*MOLS
#define NORB 192               // 4*MOLS
#define PPM 1128               // pairs per molecule = 48*47/2
#define NPAIR 288768           // NMOL*PPM
#define MATSZ 36864            // NORB*NORB
#define EVC 27.21f

// output offsets (floats)
#define F_OFF   0
#define E_OFF   9437184
#define P_OFF   9486336
#define H_OFF   18923520
#define WMAT_OFF 28360704
#define CHG_OFF 57237504
#define NCV_OFF 57249792

__device__ __forceinline__ int pairoff(int i, int j) {
    return 47 * i - (i * (i - 1)) / 2 + (j - i - 1);
}

// ---------------- per-pair: w_ss + Hcore off-diagonal blocks ----------------
__global__ void pair_kernel(
    const int* __restrict__ idxi, const int* __restrict__ idxj,
    const float* __restrict__ xij, const float* __restrict__ rij,
    const float* __restrict__ zeta_s, const float* __restrict__ zeta_p,
    const float* __restrict__ g_ss,
    const float* __restrict__ beta_s, const float* __restrict__ beta_p,
    float* __restrict__ wss, float* __restrict__ H)
{
    int pp = blockIdx.x * blockDim.x + threadIdx.x;
    if (pp >= NPAIR) return;
    int i = idxi[pp], j = idxj[pp];
    float r = rij[pp];
    float rho = 7.0f / g_ss[i] + 7.0f / g_ss[j];
    float base = 1.0f / sqrtf(r * r + rho * rho);
    float wv = EVC * base;
    wss[pp] = wv;

    float x[3] = { xij[pp * 3 + 0], xij[pp * 3 + 1], xij[pp * 3 + 2] };
    float zsi = zeta_s[i], zpi = zeta_p[i], zsj = zeta_s[j], zpj = zeta_p[j];
    float e_ss = expf(-0.5f * (zsi + zsj) * r);
    float e_sp = expf(-0.5f * (zsi + zpj) * r);
    float e_ps = expf(-0.5f * (zpi + zsj) * r);
    float e_pp = expf(-0.5f * (zpi + zpj) * r);

    float S[4][4];
    S[0][0] = e_ss;
    #pragma unroll
    for (int k = 0; k < 3; ++k) {
        S[0][1 + k] = x[k] * e_sp;
        S[1 + k][0] = -x[k] * e_ps;
        #pragma unroll
        for (int l = 0; l < 3; ++l)
            S[1 + k][1 + l] = ((k == l ? 1.0f : 0.0f) - x[k] * x[l]) * e_pp;
    }
    float boi[4] = { beta_s[i], beta_p[i], beta_p[i], beta_p[i] };
    float boj[4] = { beta_s[j], beta_p[j], beta_p[j], beta_p[j] };

    int mol = i / MOLS, ai = i % MOLS, aj = j % MOLS;
    float* Hm = H + (size_t)mol * MATSZ;
    #pragma unroll
    for (int p = 0; p < 4; ++p)
        #pragma unroll
        for (int q = 0; q < 4; ++q) {
            float v = 0.5f * (boi[p] + boj[q]) * S[p][q];
            Hm[(4 * ai + p) * NORB + 4 * aj + q] = v;
            Hm[(4 * aj + q) * NORB + 4 * ai + p] = v;
        }
}

// ---------------- w output (coalesced) ----------------
__global__ void wout_kernel(const float* __restrict__ wss, float* __restrict__ w_out)
{
    int idx = blockIdx.x * blockDim.x + threadIdx.x;
    if (idx >= NPAIR * 100) return;
    int pp = idx / 100, ab = idx % 100;
    int a = ab / 10, b = ab % 10;
    w_out[idx] = wss[pp] * (1.0f + 0.05f * (float)a) * (1.0f + 0.05f * (float)b);
}

// ---------------- per-atom: vatt gather + Hcore diagonal blocks ----------------
__global__ void atom_kernel(const int* __restrict__ Z,
    const float* __restrict__ U_ss, const float* __restrict__ U_pp,
    const float* __restrict__ wss, float* __restrict__ H)
{
    int a = blockIdx.x * blockDim.x + threadIdx.x;
    if (a >= NATOMS) return;
    int mol = a / MOLS, ai = a % MOLS;
    const float* wm = wss + mol * PPM;
    float vatt = 0.0f;
    for (int j = 0; j < MOLS; ++j) {
        if (j == ai) continue;
        int i_ = ai < j ? ai : j;
        int j_ = ai < j ? j : ai;
        float torej = (float)(Z[mol * MOLS + j] - 2);
        vatt -= torej * wm[pairoff(i_, j_)];
    }
    float u0 = U_ss[a], u1 = U_pp[a];
    float* Hm = H + (size_t)mol * MATSZ;
    #pragma unroll
    for (int p = 0; p < 4; ++p)
        #pragma unroll
        for (int q = 0; q < 4; ++q)
            Hm[(4 * ai + p) * NORB + 4 * ai + q] =
                (p == q) ? ((p == 0 ? u0 : u1) + vatt) : 0.0f;
}

// ---------------- initial density ----------------
__global__ void pinit_kernel(const int* __restrict__ Z, float* __restrict__ P)
{
    int idx = blockIdx.x * blockDim.x + threadIdx.x;
    if (idx >= NMOL * MATSZ) return;
    int mol = idx / MATSZ, rem = idx % MATSZ;
    int r = rem / NORB, c = rem % NORB;
    float v = 0.0f;
    if (r == c) v = (float)(Z[mol * MOLS + r / 4] - 2) * 0.25f;
    P[idx] = v;
}

// ---------------- Ptot (trace of diagonal density block) ----------------
__global__ void ptot_kernel(const float* __restrict__ P, float* __restrict__ Ptot)
{
    int a = blockIdx.x * blockDim.x + threadIdx.x;
    if (a >= NATOMS) return;
    int mol = a / MOLS, ai = a % MOLS;
    const float* Pm = P + (size_t)mol * MATSZ;
    float t = 0.0f;
    #pragma unroll
    for (int p = 0; p < 4; ++p) t += Pm[(4 * ai + p) * NORB + 4 * ai + p];
    Ptot[a] = t;
}

// ---------------- Fock diagonal blocks ----------------
__global__ void fockdiag_kernel(
    const float* __restrict__ P, const float* __restrict__ H, float* __restrict__ F,
    const float* __restrict__ Ptot, const float* __restrict__ wss,
    const float* __restrict__ g_ss, const float* __restrict__ g_sp,
    const float* __restrict__ g_pp, const float* __restrict__ g_p2,
    const float* __restrict__ h_sp)
{
    int a = blockIdx.x * blockDim.x + threadIdx.x;
    if (a >= NATOMS) return;
    int mol = a / MOLS, ai = a % MOLS;
    const float* wm = wss + mol * PPM;
    const float* ptm = Ptot + mol * MOLS;
    float vc = 0.0f;
    for (int j = 0; j < MOLS; ++j) {
        if (j == ai) continue;
        int i_ = ai < j ? ai : j;
        int j_ = ai < j ? j : ai;
        vc += wm[pairoff(i_, j_)] * ptm[j];
    }
    const float* Pm = P + (size_t)mol * MATSZ;
    float Pd[4][4];
    #pragma unroll
    for (int p = 0; p < 4; ++p)
        #pragma unroll
        for (int q = 0; q < 4; ++q)
            Pd[p][q] = Pm[(4 * ai + p) * NORB + 4 * ai + q];

    float Pss = Pd[0][0];
    float Pp0 = Pd[1][1], Pp1 = Pd[2][2], Pp2 = Pd[3][3];
    float Ppp = Pp0 + Pp1 + Pp2;
    float gss = g_ss[a], gsp = g_sp[a], gpp = g_pp[a], gp2 = g_p2[a], hsp = h_sp[a];
    float csp = 1.5f * hsp - 0.5f * gsp;
    float gsp_h = gsp - 0.5f * hsp;
    float fss = 0.5f * Pss * gss + Ppp * gsp_h;
    float cp = 1.25f * gp2 - 0.25f * gpp;
    float fpp0 = Pss * gsp_h + 0.5f * Pp0 * gpp + (Ppp - Pp0) * cp;
    float fpp1 = Pss * gsp_h + 0.5f * Pp1 * gpp + (Ppp - Pp1) * cp;
    float fpp2 = Pss * gsp_h + 0.5f * Pp2 * gpp + (Ppp - Pp2) * cp;
    float coff = 0.75f * gpp - 1.25f * gp2;

    float Fd[4][4];
    Fd[0][0] = fss + vc;
    Fd[1][1] = fpp0 + vc; Fd[2][2] = fpp1 + vc; Fd[3][3] = fpp2 + vc;
    #pragma unroll
    for (int k = 0; k < 3; ++k) {
        Fd[0][1 + k] = Pd[0][1 + k] * csp;
        Fd[1 + k][0] = Pd[1 + k][0] * csp;
    }
    Fd[1][2] = coff * Pd[1][2]; Fd[1][3] = coff * Pd[1][3];
    Fd[2][1] = coff * Pd[2][1]; Fd[2][3] = coff * Pd[2][3];
    Fd[3][1] = coff * Pd[3][1]; Fd[3][2] = coff * Pd[3][2];

    const float* Hm = H + (size_t)mol * MATSZ;
    float* Fm = F + (size_t)mol * MATSZ;
    #pragma unroll
    for (int p = 0; p < 4; ++p)
        #pragma unroll
        for (int q = 0; q < 4; ++q) {
            int ix = (4 * ai + p) * NORB + 4 * ai + q;
            Fm[ix] = Hm[ix] + Fd[p][q];
        }
}

// ---------------- Fock off-diagonal blocks ----------------
__global__ void fockoff_kernel(const int* __restrict__ idxi, const int* __restrict__ idxj,
    const float* __restrict__ P, const float* __restrict__ H, float* __restrict__ F,
    const float* __restrict__ wss)
{
    int pp = blockIdx.x * blockDim.x + threadIdx.x;
    if (pp >= NPAIR) return;
    int i = idxi[pp], j = idxj[pp];
    int mol = i / MOLS, ai = i % MOLS, aj = j % MOLS;
    float wv = wss[pp];
    const float* Pm = P + (size_t)mol * MATSZ;
    const float* Hm = H + (size_t)mol * MATSZ;
    float* Fm = F + (size_t)mol * MATSZ;
    #pragma unroll
    for (int p = 0; p < 4; ++p)
        #pragma unroll
        for (int q = 0; q < 4; ++q) {
            int ij = (4 * ai + p) * NORB + 4 * aj + q;
            int ji = (4 * aj + q) * NORB + 4 * ai + p;
            float f = -0.5f * wv * Pm[ij];
            Fm[ij] = Hm[ij] + f;
            Fm[ji] = Hm[ji] + f;
        }
}

// ---------------- batched eigensolver: one-sided Jacobi on sigma*I - F ----------------
// warm=1: start from B = (sigma*I - F) * Vprev. FIXED sweep count (nsweep):
// tol2=2.5e-11 (known-good numerics from R1/R2) is kept only as a write-skip;
// no convergence test (it never fires at this tol -> caps were always hit anyway).
#define EIG_T 768
#define ESTR 196     // padded column stride in floats
#define ESTR4 49     // in float4
#define EIG_LDS (( (ESTR*NORB) + 2*NORB ) * 4 + NORB * 4)

__global__ void __launch_bounds__(EIG_T)
eigh_kernel(const float* __restrict__ Fg, const int* __restrict__ noccA,
            const float* __restrict__ Vin, float* __restrict__ Vout,
            float* __restrict__ Wout, float* __restrict__ eout,
            int mode, int warm, int nsweep)
{
    extern __shared__ float sm[];
    float* B = sm;                          // ESTR*NORB
    float* colv = sm + ESTR * NORB;         // NORB
    float* colv2 = colv + NORB;             // NORB
    int* slot = (int*)(colv2 + NORB);       // NORB
    __shared__ float sigma;

    const int mol = blockIdx.x;
    const int tid = threadIdx.x;
    const int team = tid >> 3, lane = tid & 7;
    const float* Fm = Fg + (size_t)mol * MATSZ;

    if (!warm) {
        // cold: load F into LDS (padded columns; symmetric so col-major == row-major)
        for (int i4 = tid; i4 < NORB * 48; i4 += EIG_T) {
            int c = i4 / 48, r4 = i4 % 48;
            ((float4*)B)[c * ESTR4 + r4] = ((const float4*)Fm)[i4];
        }
        __syncthreads();
        // Gershgorin per column from LDS
        {
            int c = tid >> 2, part = tid & 3;
            const float4* col = (const float4*)B + c * ESTR4 + part * 12;
            float s = 0.0f;
            #pragma unroll
            for (int u = 0; u < 12; ++u) {
                float4 v = col[u];
                s += fabsf(v.x) + fabsf(v.y) + fabsf(v.z) + fabsf(v.w);
            }
            s += __shfl_xor(s, 1); s += __shfl_xor(s, 2);
            if (part == 0) { float d = B[c * ESTR + c]; colv[c] = s - fabsf(d) + d; }
        }
        __syncthreads();
        if (tid < 64) {
            float m = -3.4e38f;
            for (int i = tid; i < NORB; i += 64) m = fmaxf(m, colv[i]);
            #pragma unroll
            for (int o = 32; o >= 1; o >>= 1) m = fmaxf(m, __shfl_xor(m, o));
            if (tid == 0) sigma = m + 1.0f + 1e-3f * fabsf(m);
        }
        __syncthreads();
        float sg = sigma;
        // B = sigma*I - F
        for (int i4 = tid; i4 < NORB * 48; i4 += EIG_T) {
            int c = i4 / 48, r4 = i4 % 48;
            float4* pv = (float4*)B + c * ESTR4 + r4;
            float4 v = *pv;
            v.x = -v.x; v.y = -v.y; v.z = -v.z; v.w = -v.w;
            *pv = v;
        }
        __syncthreads();
        if (tid < NORB) B[tid * ESTR + tid] += sg;
        __syncthreads();
    } else {
        // warm: load Vprev into LDS
        for (int i4 = tid; i4 < NORB * 48; i4 += EIG_T) {
            int c = i4 / 48, r4 = i4 % 48;
            ((float4*)B)[c * ESTR4 + r4] = ((const float4*)Vin)[(size_t)mol * (MATSZ / 4) + i4];
        }
        // Gershgorin per column from GLOBAL F (no dependency on V load)
        {
            int c = tid >> 2, part = tid & 3;
            const float4* col = (const float4*)(Fm + c * NORB) + part * 12;
            float s = 0.0f;
            #pragma unroll
            for (int u = 0; u < 12; ++u) {
                float4 v = col[u];
                s += fabsf(v.x) + fabsf(v.y) + fabsf(v.z) + fabsf(v.w);
            }
            s += __shfl_xor(s, 1); s += __shfl_xor(s, 2);
            if (part == 0) { float d = Fm[c * NORB + c]; colv[c] = s - fabsf(d) + d; }
        }
        __syncthreads();
        if (tid < 64) {
            float m = -3.4e38f;
            for (int i = tid; i < NORB; i += 64) m = fmaxf(m, colv[i]);
            #pragma unroll
            for (int o = 32; o >= 1; o >>= 1) m = fmaxf(m, __shfl_xor(m, o));
            if (tid == 0) sigma = m + 1.0f + 1e-3f * fabsf(m);
        }
        __syncthreads();
        float sg = sigma;
        // B[:,j] = sg*V[:,j] - F*V[:,j]; team handles cols 2t,2t+1 (reads only own cols).
        {
            int j0 = 2 * team, j1 = j0 + 1;
            float4 acc0[6], acc1[6];
            #pragma unroll
            for (int u = 0; u < 6; ++u) {
                acc0[u].x = acc0[u].y = acc0[u].z = acc0[u].w = 0.0f;
                acc1[u].x = acc1[u].y = acc1[u].z = acc1[u].w = 0.0f;
            }
            const float4* F4 = (const float4*)Fm;
            for (int k = 0; k < NORB; ++k) {
                float v0 = B[j0 * ESTR + k];
                float v1 = B[j1 * ESTR + k];
                const float4* Fk = F4 + k * 48 + lane;
                #pragma unroll
                for (int u = 0; u < 6; ++u) {
                    float4 f = Fk[8 * u];
                    acc0[u].x += f.x * v0; acc0[u].y += f.y * v0;
                    acc0[u].z += f.z * v0; acc0[u].w += f.w * v0;
                    acc1[u].x += f.x * v1; acc1[u].y += f.y * v1;
                    acc1[u].z += f.z * v1; acc1[u].w += f.w * v1;
                }
            }
            #pragma unroll
            for (int u = 0; u < 6; ++u) {
                int r4 = lane + 8 * u;
                float4* pa = (float4*)B + j0 * ESTR4 + r4;
                float4* pb = (float4*)B + j1 * ESTR4 + r4;
                float4 va = *pa, vb = *pb, oa, ob;
                oa.x = sg * va.x - acc0[u].x; oa.y = sg * va.y - acc0[u].y;
                oa.z = sg * va.z - acc0[u].z; oa.w = sg * va.w - acc0[u].w;
                ob.x = sg * vb.x - acc1[u].x; ob.y = sg * vb.y - acc1[u].y;
                ob.z = sg * vb.z - acc1[u].z; ob.w = sg * vb.w - acc1[u].w;
                *pa = oa; *pb = ob;
            }
        }
        __syncthreads();
    }
    float sg = sigma;

    // one-sided Jacobi sweeps, tournament ordering (96 disjoint pairs/round),
    // FIXED sweep count.
    const float tol2 = 2.5e-11f;   // write-skip only (R1/R2-validated numerics)
    for (int sweep = 0; sweep < nsweep; ++sweep) {
        int p, q;
        if (team == 0) { p = NORB - 1; q = 0; }
        else           { p = team;     q = (NORB - 1) - team; }
        for (int r = 0; r < NORB - 1; ++r) {
            float4* bp = (float4*)B + p * ESTR4 + lane;
            float4* bq = (float4*)B + q * ESTR4 + lane;
            float4 xp[6], xq[6];
            #pragma unroll
            for (int u = 0; u < 6; ++u) { xp[u] = bp[8 * u]; xq[u] = bq[8 * u]; }
            float app = 0.f, aqq = 0.f, apq = 0.f;
            #pragma unroll
            for (int u = 0; u < 6; ++u) {
                app += xp[u].x * xp[u].x + xp[u].y * xp[u].y + xp[u].z * xp[u].z + xp[u].w * xp[u].w;
                aqq += xq[u].x * xq[u].x + xq[u].y * xq[u].y + xq[u].z * xq[u].z + xq[u].w * xq[u].w;
                apq += xp[u].x * xq[u].x + xp[u].y * xq[u].y + xp[u].z * xq[u].z + xp[u].w * xq[u].w;
            }
            app += __shfl_xor(app, 1); app += __shfl_xor(app, 2); app += __shfl_xor(app, 4);
            aqq += __shfl_xor(aqq, 1); aqq += __shfl_xor(aqq, 2); aqq += __shfl_xor(aqq, 4);
            apq += __shfl_xor(apq, 1); apq += __shfl_xor(apq, 2); apq += __shfl_xor(apq, 4);
            if (apq * apq > tol2 * app * aqq) {
                float zeta = (aqq - app) / (2.0f * apq);
                float t = copysignf(1.0f, zeta) / (fabsf(zeta) + sqrtf(1.0f + zeta * zeta));
                float cc = 1.0f / sqrtf(1.0f + t * t);
                float ss = t * cc;
                #pragma unroll
                for (int u = 0; u < 6; ++u) {
                    float4 av = xp[u], bv = xq[u], na, nb;
                    na.x = cc * av.x - ss * bv.x;  nb.x = ss * av.x + cc * bv.x;
                    na.y = cc * av.y - ss * bv.y;  nb.y = ss * av.y + cc * bv.y;
                    na.z = cc * av.z - ss * bv.z;  nb.z = ss * av.z + cc * bv.z;
                    na.w = cc * av.w - ss * bv.w;  nb.w = ss * av.w + cc * bv.w;
                    bp[8 * u] = na; bq[8 * u] = nb;
                }
            }
            __syncthreads();
            if (team != 0) p = (p == NORB - 2) ? 0 : p + 1;
            q = (q == NORB - 2) ? 0 : q + 1;
        }
    }

    // column norms^2
    {
        int c = tid >> 2, part = tid & 3;
        const float4* col = (const float4*)B + c * ESTR4 + part * 12;
        float s = 0.0f;
        #pragma unroll
        for (int u = 0; u < 12; ++u) {
            float4 v = col[u];
            s += v.x * v.x + v.y * v.y + v.z * v.z + v.w * v.w;
        }
        s += __shfl_xor(s, 1); s += __shfl_xor(s, 2);
        if (part == 0) colv[c] = s;
    }
    __syncthreads();

    if (mode == 0) {
        // occupied = nocc largest norms (= smallest eigenvalues of F)
        int noccm = noccA[mol];
        if (tid < NORB) {
            float nc = colv[tid];
            int rank = 0;
            for (int j2 = 0; j2 < NORB; ++j2) {
                float nj = colv[j2];
                rank += (nj > nc) || (nj == nc && j2 < tid);
            }
            slot[tid] = rank;
            colv2[tid] = rsqrtf(nc);     // 1/||b||
        }
        __syncthreads();
        float* Wm = Wout + (size_t)mol * MATSZ;
        float* Vm = Vout + (size_t)mol * MATSZ;
        for (int i4 = tid; i4 < NORB * 48; i4 += EIG_T) {
            int c = i4 / 48, r4 = i4 % 48;
            float inv = colv2[c];
            float4 v = ((float4*)B)[c * ESTR4 + r4];
            float4 nv;
            nv.x = v.x * inv; nv.y = v.y * inv; nv.z = v.z * inv; nv.w = v.w * inv;
            ((float4*)Vm)[i4] = nv;      // full basis for next warm start
            int sl = slot[c];
            if (sl < noccm) {
                float4 o;
                o.x = nv.x * 1.41421356f; o.y = nv.y * 1.41421356f;
                o.z = nv.z * 1.41421356f; o.w = nv.w * 1.41421356f;
                ((float4*)Wm)[sl * 48 + r4] = o;
            }
        }
    } else {
        // eigenvalues ascending
        if (tid < NORB) colv2[tid] = sg - sqrtf(colv[tid]);
        __syncthreads();
        if (tid < NORB) {
            float ec = colv2[tid];
            int rank = 0;
            for (int j2 = 0; j2 < NORB; ++j2) {
                float ej = colv2[j2];
                rank += (ej < ec) || (ej == ec && j2 < tid);
            }
            eout[mol * NORB + rank] = ec;
        }
    }
}

// ---------------- Pnew = W^T W, mix, err ----------------
__global__ void __launch_bounds__(256)
pmix_kernel(const float* __restrict__ W, const int* __restrict__ noccA,
            float* __restrict__ P, unsigned int* __restrict__ err, int last)
{
    int mol = blockIdx.x / 36;
    int tile = blockIdx.x % 36;
    int i0 = (tile / 6) * 32, j0 = (tile % 6) * 32;
    int K = noccA[mol];
    const float* Wm = W + (size_t)mol * MATSZ;
    __shared__ float As[32][33];
    __shared__ float Bs[32][33];
    int t = threadIdx.x;
    int ty = t >> 4, tx = t & 15;
    float acc00 = 0.f, acc01 = 0.f, acc10 = 0.f, acc11 = 0.f;
    for (int k0 = 0; k0 < K; k0 += 32) {
        for (int l = t; l < 1024; l += 256) {
            int k = l >> 5, idx = l & 31;
            bool ok = (k0 + k) < K;
            As[k][idx] = ok ? Wm[(k0 + k) * NORB + i0 + idx] : 0.0f;
            Bs[k][idx] = ok ? Wm[(k0 + k) * NORB + j0 + idx] : 0.0f;
        }
        __syncthreads();
        #pragma unroll 8
        for (int k = 0; k < 32; ++k) {
            float a0 = As[k][2 * ty], a1 = As[k][2 * ty + 1];
            float b0 = Bs[k][2 * tx], b1 = Bs[k][2 * tx + 1];
            acc00 += a0 * b0; acc01 += a0 * b1; acc10 += a1 * b0; acc11 += a1 * b1;
        }
        __syncthreads();
    }
    float* Pm = P + (size_t)mol * MATSZ;
    float lmax = 0.0f;
    int ib = i0 + 2 * ty, jb = j0 + 2 * tx;
    {
        float po, pn;
        po = Pm[ib * NORB + jb];           pn = acc00; lmax = fmaxf(lmax, fabsf(pn - po)); Pm[ib * NORB + jb] = 0.5f * (po + pn);
        po = Pm[ib * NORB + jb + 1];       pn = acc01; lmax = fmaxf(lmax, fabsf(pn - po)); Pm[ib * NORB + jb + 1] = 0.5f * (po + pn);
        po = Pm[(ib + 1) * NORB + jb];     pn = acc10; lmax = fmaxf(lmax, fabsf(pn - po)); Pm[(ib + 1) * NORB + jb] = 0.5f * (po + pn);
        po = Pm[(ib + 1) * NORB + jb + 1]; pn = acc11; lmax = fmaxf(lmax, fabsf(pn - po)); Pm[(ib + 1) * NORB + jb + 1] = 0.5f * (po + pn);
    }
    if (last) {
        #pragma unroll
        for (int o = 32; o >= 1; o >>= 1) lmax = fmaxf(lmax, __shfl_xor(lmax, o));
        __shared__ float wm4[4];
        if ((t & 63) == 0) wm4[t >> 6] = lmax;
        __syncthreads();
        if (t == 0) {
            float m = fmaxf(fmaxf(wm4[0], wm4[1]), fmaxf(wm4[2], wm4[3]));
            atomicMax(err + mol, __float_as_uint(m));
        }
    }
}

// ---------------- charge + notconverged ----------------
__global__ void finish_kernel(const int* __restrict__ Z, const float* __restrict__ P,
    const float* __restrict__ errf, float* __restrict__ chg, float* __restrict__ ncv)
{
    int a = blockIdx.x * blockDim.x + threadIdx.x;
    if (a < NATOMS) {
        int mol = a / MOLS, ai = a % MOLS;
        const float* Pm = P + (size_t)mol * MATSZ;
        float tr = 0.0f;
        #pragma unroll
        for (int p = 0; p < 4; ++p) tr += Pm[(4 * ai + p) * NORB + 4 * ai + p];
        chg[a] = (float)(Z[a] - 2) - tr;
    }
    if (a < NMOL) ncv[a] = (errf[a] > 1e-6f) ? 1.0f : 0.0f;
}

extern "C" void kernel_launch(void* const* d_in, const int* in_sizes, int n_in,
                              void* d_out, int out_size, void* d_ws, size_t ws_size,
                              hipStream_t stream)
{
    (void)in_sizes; (void)n_in; (void)out_size; (void)ws_size;

    const int*   nocc   = (const int*)d_in[3];
    const int*   Z      = (const int*)d_in[4];
    const int*   idxi   = (const int*)d_in[9];
    const int*   idxj   = (const int*)d_in[10];
    const float* xij    = (const float*)d_in[13];
    const float* rij    = (const float*)d_in[14];
    const float* zeta_s = (const float*)d_in[15];
    const float* zeta_p = (const float*)d_in[16];
    const float* U_ss   = (const float*)d_in[17];
    const float* U_pp   = (const float*)d_in[18];
    const float* g_ss   = (const float*)d_in[19];
    const float* g_sp   = (const float*)d_in[20];
    const float* g_pp   = (const float*)d_in[21];
    const float* g_p2   = (const float*)d_in[22];
    const float* h_sp   = (const float*)d_in[23];
    const float* beta_s = (const float*)d_in[24];
    const float* beta_p = (const float*)d_in[25];

    float* out     = (float*)d_out;
    float* F_out   = out + F_OFF;
    float* e_out   = out + E_OFF;
    float* P_out   = out + P_OFF;
    float* H_out   = out + H_OFF;
    float* w_out   = out + WMAT_OFF;
    float* chg_out = out + CHG_OFF;
    float* ncv_out = out + NCV_OFF;

    // V basis (37.75MB) lives in the w output region (115.5MB) during SCF;
    // wout_kernel runs LAST to restore the correct w contents.
    float* Vbuf = w_out;

    char* wsb = (char*)d_ws;
    float* Wocc = (float*)wsb;                                  // 37,748,736 B
    float* wss  = (float*)(wsb + 37748736);                     //  1,155,072 B
    float* Ptot = (float*)(wsb + 37748736 + 1155072);           //     49,152 B
    unsigned int* err = (unsigned int*)(wsb + 37748736 + 1155072 + 49152);

    hipMemsetAsync(err, 0, NMOL * sizeof(unsigned int), stream);

    hipFuncSetAttribute(reinterpret_cast<const void*>(eigh_kernel),
                        hipFuncAttributeMaxDynamicSharedMemorySize, EIG_LDS);

    pair_kernel<<<NPAIR / 256, 256, 0, stream>>>(idxi, idxj, xij, rij, zeta_s, zeta_p,
                                                 g_ss, beta_s, beta_p, wss, H_out);
    atom_kernel<<<NATOMS / 256, 256, 0, stream>>>(Z, U_ss, U_pp, wss, H_out);
    pinit_kernel<<<(NMOL * MATSZ) / 256, 256, 0, stream>>>(Z, P_out);

    // fixed sweep schedule: cold 12; warm decreasing; final eigenvalue solve 4
    const int sweeps[9] = {12, 7, 5, 4, 4, 4, 4, 4, 4};

    for (int it = 0; it < 9; ++it) {
        ptot_kernel<<<NATOMS / 256, 256, 0, stream>>>(P_out, Ptot);
        fockdiag_kernel<<<NATOMS / 256, 256, 0, stream>>>(P_out, H_out, F_out, Ptot, wss,
                                                          g_ss, g_sp, g_pp, g_p2, h_sp);
        fockoff_kernel<<<NPAIR / 256, 256, 0, stream>>>(idxi, idxj, P_out, H_out, F_out, wss);
        if (it < 8) {
            eigh_kernel<<<NMOL, EIG_T, EIG_LDS, stream>>>(F_out, nocc, Vbuf, Vbuf,
                                                          Wocc, e_out, 0, it > 0 ? 1 : 0,
                                                          sweeps[it]);
            pmix_kernel<<<NMOL * 36, 256, 0, stream>>>(Wocc, nocc, P_out, err, (it == 7) ? 1 : 0);
        } else {
            eigh_kernel<<<NMOL, EIG_T, EIG_LDS, stream>>>(F_out, nocc, Vbuf, Vbuf,
                                                          Wocc, e_out, 1, 1, sweeps[8]);
        }
    }
    finish_kernel<<<NATOMS / 256, 256, 0, stream>>>(Z, P_out, (const float*)err, chg_out, ncv_out);
    wout_kernel<<<(NPAIR * 100) / 256, 256, 0, stream>>>(wss, w_out);
}

// Round 6
// 55329.309 us; speedup vs baseline: 1.6100x; 1.2109x over previous
//
#include <hip/hip_runtime.h>

#define NMOL 256
#define MOLS 48
#define NATOMS 12288           // NMOL*MOLS
#define NORB 192               // 4*MOLS
#define PPM 1128               // pairs per molecule = 48*47/2
#define NPAIR 288768           // NMOL*PPM
#define MATSZ 36864            // NORB*NORB
#define EVC 27.21f

// output offsets (floats)
#define F_OFF   0
#define E_OFF   9437184
#define P_OFF   9486336
#define H_OFF   18923520
#define WMAT_OFF 28360704
#define CHG_OFF 57237504
#define NCV_OFF 57249792

__device__ __forceinline__ int pairoff(int i, int j) {
    return 47 * i - (i * (i - 1)) / 2 + (j - i - 1);
}

// ---------------- per-pair: w_ss + Hcore off-diagonal blocks ----------------
__global__ void pair_kernel(
    const int* __restrict__ idxi, const int* __restrict__ idxj,
    const float* __restrict__ xij, const float* __restrict__ rij,
    const float* __restrict__ zeta_s, const float* __restrict__ zeta_p,
    const float* __restrict__ g_ss,
    const float* __restrict__ beta_s, const float* __restrict__ beta_p,
    float* __restrict__ wss, float* __restrict__ H)
{
    int pp = blockIdx.x * blockDim.x + threadIdx.x;
    if (pp >= NPAIR) return;
    int i = idxi[pp], j = idxj[pp];
    float r = rij[pp];
    float rho = 7.0f / g_ss[i] + 7.0f / g_ss[j];
    float base = 1.0f / sqrtf(r * r + rho * rho);
    float wv = EVC * base;
    wss[pp] = wv;

    float x[3] = { xij[pp * 3 + 0], xij[pp * 3 + 1], xij[pp * 3 + 2] };
    float zsi = zeta_s[i], zpi = zeta_p[i], zsj = zeta_s[j], zpj = zeta_p[j];
    float e_ss = expf(-0.5f * (zsi + zsj) * r);
    float e_sp = expf(-0.5f * (zsi + zpj) * r);
    float e_ps = expf(-0.5f * (zpi + zsj) * r);
    float e_pp = expf(-0.5f * (zpi + zpj) * r);

    float S[4][4];
    S[0][0] = e_ss;
    #pragma unroll
    for (int k = 0; k < 3; ++k) {
        S[0][1 + k] = x[k] * e_sp;
        S[1 + k][0] = -x[k] * e_ps;
        #pragma unroll
        for (int l = 0; l < 3; ++l)
            S[1 + k][1 + l] = ((k == l ? 1.0f : 0.0f) - x[k] * x[l]) * e_pp;
    }
    float boi[4] = { beta_s[i], beta_p[i], beta_p[i], beta_p[i] };
    float boj[4] = { beta_s[j], beta_p[j], beta_p[j], beta_p[j] };

    int mol = i / MOLS, ai = i % MOLS, aj = j % MOLS;
    float* Hm = H + (size_t)mol * MATSZ;
    #pragma unroll
    for (int p = 0; p < 4; ++p)
        #pragma unroll
        for (int q = 0; q < 4; ++q) {
            float v = 0.5f * (boi[p] + boj[q]) * S[p][q];
            Hm[(4 * ai + p) * NORB + 4 * aj + q] = v;
            Hm[(4 * aj + q) * NORB + 4 * ai + p] = v;
        }
}

// ---------------- w output (coalesced) ----------------
__global__ void wout_kernel(const float* __restrict__ wss, float* __restrict__ w_out)
{
    int idx = blockIdx.x * blockDim.x + threadIdx.x;
    if (idx >= NPAIR * 100) return;
    int pp = idx / 100, ab = idx % 100;
    int a = ab / 10, b = ab % 10;
    w_out[idx] = wss[pp] * (1.0f + 0.05f * (float)a) * (1.0f + 0.05f * (float)b);
}

// ---------------- per-atom: vatt gather + Hcore diagonal blocks ----------------
__global__ void atom_kernel(const int* __restrict__ Z,
    const float* __restrict__ U_ss, const float* __restrict__ U_pp,
    const float* __restrict__ wss, float* __restrict__ H)
{
    int a = blockIdx.x * blockDim.x + threadIdx.x;
    if (a >= NATOMS) return;
    int mol = a / MOLS, ai = a % MOLS;
    const float* wm = wss + mol * PPM;
    float vatt = 0.0f;
    for (int j = 0; j < MOLS; ++j) {
        if (j == ai) continue;
        int i_ = ai < j ? ai : j;
        int j_ = ai < j ? j : ai;
        float torej = (float)(Z[mol * MOLS + j] - 2);
        vatt -= torej * wm[pairoff(i_, j_)];
    }
    float u0 = U_ss[a], u1 = U_pp[a];
    float* Hm = H + (size_t)mol * MATSZ;
    #pragma unroll
    for (int p = 0; p < 4; ++p)
        #pragma unroll
        for (int q = 0; q < 4; ++q)
            Hm[(4 * ai + p) * NORB + 4 * ai + q] =
                (p == q) ? ((p == 0 ? u0 : u1) + vatt) : 0.0f;
}

// ---------------- initial density ----------------
__global__ void pinit_kernel(const int* __restrict__ Z, float* __restrict__ P)
{
    int idx = blockIdx.x * blockDim.x + threadIdx.x;
    if (idx >= NMOL * MATSZ) return;
    int mol = idx / MATSZ, rem = idx % MATSZ;
    int r = rem / NORB, c = rem % NORB;
    float v = 0.0f;
    if (r == c) v = (float)(Z[mol * MOLS + r / 4] - 2) * 0.25f;
    P[idx] = v;
}

// ---------------- Ptot (trace of diagonal density block) ----------------
__global__ void ptot_kernel(const float* __restrict__ P, float* __restrict__ Ptot)
{
    int a = blockIdx.x * blockDim.x + threadIdx.x;
    if (a >= NATOMS) return;
    int mol = a / MOLS, ai = a % MOLS;
    const float* Pm = P + (size_t)mol * MATSZ;
    float t = 0.0f;
    #pragma unroll
    for (int p = 0; p < 4; ++p) t += Pm[(4 * ai + p) * NORB + 4 * ai + p];
    Ptot[a] = t;
}

// ---------------- Fock diagonal blocks ----------------
__global__ void fockdiag_kernel(
    const float* __restrict__ P, const float* __restrict__ H, float* __restrict__ F,
    const float* __restrict__ Ptot, const float* __restrict__ wss,
    const float* __restrict__ g_ss, const float* __restrict__ g_sp,
    const float* __restrict__ g_pp, const float* __restrict__ g_p2,
    const float* __restrict__ h_sp)
{
    int a = blockIdx.x * blockDim.x + threadIdx.x;
    if (a >= NATOMS) return;
    int mol = a / MOLS, ai = a % MOLS;
    const float* wm = wss + mol * PPM;
    const float* ptm = Ptot + mol * MOLS;
    float vc = 0.0f;
    for (int j = 0; j < MOLS; ++j) {
        if (j == ai) continue;
        int i_ = ai < j ? ai : j;
        int j_ = ai < j ? j : ai;
        vc += wm[pairoff(i_, j_)] * ptm[j];
    }
    const float* Pm = P + (size_t)mol * MATSZ;
    float Pd[4][4];
    #pragma unroll
    for (int p = 0; p < 4; ++p)
        #pragma unroll
        for (int q = 0; q < 4; ++q)
            Pd[p][q] = Pm[(4 * ai + p) * NORB + 4 * ai + q];

    float Pss = Pd[0][0];
    float Pp0 = Pd[1][1], Pp1 = Pd[2][2], Pp2 = Pd[3][3];
    float Ppp = Pp0 + Pp1 + Pp2;
    float gss = g_ss[a], gsp = g_sp[a], gpp = g_pp[a], gp2 = g_p2[a], hsp = h_sp[a];
    float csp = 1.5f * hsp - 0.5f * gsp;
    float gsp_h = gsp - 0.5f * hsp;
    float fss = 0.5f * Pss * gss + Ppp * gsp_h;
    float cp = 1.25f * gp2 - 0.25f * gpp;
    float fpp0 = Pss * gsp_h + 0.5f * Pp0 * gpp + (Ppp - Pp0) * cp;
    float fpp1 = Pss * gsp_h + 0.5f * Pp1 * gpp + (Ppp - Pp1) * cp;
    float fpp2 = Pss * gsp_h + 0.5f * Pp2 * gpp + (Ppp - Pp2) * cp;
    float coff = 0.75f * gpp - 1.25f * gp2;

    float Fd[4][4];
    Fd[0][0] = fss + vc;
    Fd[1][1] = fpp0 + vc; Fd[2][2] = fpp1 + vc; Fd[3][3] = fpp2 + vc;
    #pragma unroll
    for (int k = 0; k < 3; ++k) {
        Fd[0][1 + k] = Pd[0][1 + k] * csp;
        Fd[1 + k][0] = Pd[1 + k][0] * csp;
    }
    Fd[1][2] = coff * Pd[1][2]; Fd[1][3] = coff * Pd[1][3];
    Fd[2][1] = coff * Pd[2][1]; Fd[2][3] = coff * Pd[2][3];
    Fd[3][1] = coff * Pd[3][1]; Fd[3][2] = coff * Pd[3][2];

    const float* Hm = H + (size_t)mol * MATSZ;
    float* Fm = F + (size_t)mol * MATSZ;
    #pragma unroll
    for (int p = 0; p < 4; ++p)
        #pragma unroll
        for (int q = 0; q < 4; ++q) {
            int ix = (4 * ai + p) * NORB + 4 * ai + q;
            Fm[ix] = Hm[ix] + Fd[p][q];
        }
}

// ---------------- Fock off-diagonal blocks ----------------
__global__ void fockoff_kernel(const int* __restrict__ idxi, const int* __restrict__ idxj,
    const float* __restrict__ P, const float* __restrict__ H, float* __restrict__ F,
    const float* __restrict__ wss)
{
    int pp = blockIdx.x * blockDim.x + threadIdx.x;
    if (pp >= NPAIR) return;
    int i = idxi[pp], j = idxj[pp];
    int mol = i / MOLS, ai = i % MOLS, aj = j % MOLS;
    float wv = wss[pp];
    const float* Pm = P + (size_t)mol * MATSZ;
    const float* Hm = H + (size_t)mol * MATSZ;
    float* Fm = F + (size_t)mol * MATSZ;
    #pragma unroll
    for (int p = 0; p < 4; ++p)
        #pragma unroll
        for (int q = 0; q < 4; ++q) {
            int ij = (4 * ai + p) * NORB + 4 * aj + q;
            int ji = (4 * aj + q) * NORB + 4 * ai + p;
            float f = -0.5f * wv * Pm[ij];
            Fm[ij] = Hm[ij] + f;
            Fm[ji] = Hm[ji] + f;
        }
}

// ---------------- batched eigensolver: one-sided Jacobi on sigma*I - F ----------------
// Super-round scheme (structure unchanged from R5): 96 super-players of 2 columns;
// 48 teams x 16 lanes; per round each team rotates its 2x2 block of column pairs.
// Sweep schedule restored to R2-equivalent uniform counts (R5 post-mortem: the SCF
// runs fixed 8 iterations without full convergence, so EARLY-iteration solver errors
// amplify through the trajectory — starving mid iterations was the failure cause).
#define EIG_T 768
#define ESTR 196     // padded column stride in floats
#define ESTR4 49     // in float4
#define EIG_LDS (( (ESTR*NORB) + 2*NORB ) * 4 + NORB * 4)

__device__ __forceinline__ float rsum16(float v) {
    v += __shfl_xor(v, 1); v += __shfl_xor(v, 2);
    v += __shfl_xor(v, 4); v += __shfl_xor(v, 8);
    return v;
}
__device__ __forceinline__ float rsum8(float v) {
    v += __shfl_xor(v, 1); v += __shfl_xor(v, 2); v += __shfl_xor(v, 4);
    return v;
}

__global__ void __launch_bounds__(EIG_T)
eigh_kernel(const float* __restrict__ Fg, const int* __restrict__ noccA,
            const float* __restrict__ Vin, float* __restrict__ Vout,
            float* __restrict__ Wout, float* __restrict__ eout,
            int mode, int warm, int nsweep)
{
    extern __shared__ float sm[];
    float* B = sm;                          // ESTR*NORB
    float* colv = sm + ESTR * NORB;         // NORB (norms^2, tracked)
    float* colv2 = colv + NORB;             // NORB
    int* slot = (int*)(colv2 + NORB);       // NORB
    __shared__ float sigma;

    const int mol = blockIdx.x;
    const int tid = threadIdx.x;
    const float* Fm = Fg + (size_t)mol * MATSZ;
    float4* B4 = (float4*)B;

    if (!warm) {
        // cold: load F into LDS (padded columns; symmetric so col-major == row-major)
        for (int i4 = tid; i4 < NORB * 48; i4 += EIG_T) {
            int c = i4 / 48, r4 = i4 % 48;
            B4[c * ESTR4 + r4] = ((const float4*)Fm)[i4];
        }
        __syncthreads();
        // Gershgorin per column from LDS
        {
            int c = tid >> 2, part = tid & 3;
            const float4* col = (const float4*)B + c * ESTR4 + part * 12;
            float s = 0.0f;
            #pragma unroll
            for (int u = 0; u < 12; ++u) {
                float4 v = col[u];
                s += fabsf(v.x) + fabsf(v.y) + fabsf(v.z) + fabsf(v.w);
            }
            s += __shfl_xor(s, 1); s += __shfl_xor(s, 2);
            if (part == 0) { float d = B[c * ESTR + c]; colv[c] = s - fabsf(d) + d; }
        }
        __syncthreads();
        if (tid < 64) {
            float m = -3.4e38f;
            for (int i = tid; i < NORB; i += 64) m = fmaxf(m, colv[i]);
            #pragma unroll
            for (int o = 32; o >= 1; o >>= 1) m = fmaxf(m, __shfl_xor(m, o));
            if (tid == 0) sigma = m + 1.0f + 1e-3f * fabsf(m);
        }
        __syncthreads();
        float sg = sigma;
        // B = sigma*I - F
        for (int i4 = tid; i4 < NORB * 48; i4 += EIG_T) {
            int c = i4 / 48, r4 = i4 % 48;
            float4* pv = B4 + c * ESTR4 + r4;
            float4 v = *pv;
            v.x = -v.x; v.y = -v.y; v.z = -v.z; v.w = -v.w;
            *pv = v;
        }
        __syncthreads();
        if (tid < NORB) B[tid * ESTR + tid] += sg;
        __syncthreads();
    } else {
        // warm: load Vprev into LDS
        for (int i4 = tid; i4 < NORB * 48; i4 += EIG_T) {
            int c = i4 / 48, r4 = i4 % 48;
            B4[c * ESTR4 + r4] = ((const float4*)Vin)[(size_t)mol * (MATSZ / 4) + i4];
        }
        // Gershgorin per column from GLOBAL F (no dependency on V load)
        {
            int c = tid >> 2, part = tid & 3;
            const float4* col = (const float4*)(Fm + c * NORB) + part * 12;
            float s = 0.0f;
            #pragma unroll
            for (int u = 0; u < 12; ++u) {
                float4 v = col[u];
                s += fabsf(v.x) + fabsf(v.y) + fabsf(v.z) + fabsf(v.w);
            }
            s += __shfl_xor(s, 1); s += __shfl_xor(s, 2);
            if (part == 0) { float d = Fm[c * NORB + c]; colv[c] = s - fabsf(d) + d; }
        }
        __syncthreads();
        if (tid < 64) {
            float m = -3.4e38f;
            for (int i = tid; i < NORB; i += 64) m = fmaxf(m, colv[i]);
            #pragma unroll
            for (int o = 32; o >= 1; o >>= 1) m = fmaxf(m, __shfl_xor(m, o));
            if (tid == 0) sigma = m + 1.0f + 1e-3f * fabsf(m);
        }
        __syncthreads();
        float sg = sigma;
        // B[:,j] = sg*V[:,j] - F*V[:,j]; 8-lane team handles cols 2t,2t+1.
        {
            int t8 = tid >> 3, l8 = tid & 7;
            int j0 = 2 * t8, j1 = j0 + 1;
            float4 acc0[6], acc1[6];
            #pragma unroll
            for (int u = 0; u < 6; ++u) {
                acc0[u].x = acc0[u].y = acc0[u].z = acc0[u].w = 0.0f;
                acc1[u].x = acc1[u].y = acc1[u].z = acc1[u].w = 0.0f;
            }
            const float4* F4 = (const float4*)Fm;
            for (int k = 0; k < NORB; ++k) {
                float v0 = B[j0 * ESTR + k];
                float v1 = B[j1 * ESTR + k];
                const float4* Fk = F4 + k * 48 + l8;
                #pragma unroll
                for (int u = 0; u < 6; ++u) {
                    float4 f = Fk[8 * u];
                    acc0[u].x += f.x * v0; acc0[u].y += f.y * v0;
                    acc0[u].z += f.z * v0; acc0[u].w += f.w * v0;
                    acc1[u].x += f.x * v1; acc1[u].y += f.y * v1;
                    acc1[u].z += f.z * v1; acc1[u].w += f.w * v1;
                }
            }
            #pragma unroll
            for (int u = 0; u < 6; ++u) {
                int r4 = l8 + 8 * u;
                float4* pa = B4 + j0 * ESTR4 + r4;
                float4* pb = B4 + j1 * ESTR4 + r4;
                float4 va = *pa, vb = *pb, oa, ob;
                oa.x = sg * va.x - acc0[u].x; oa.y = sg * va.y - acc0[u].y;
                oa.z = sg * va.z - acc0[u].z; oa.w = sg * va.w - acc0[u].w;
                ob.x = sg * vb.x - acc1[u].x; ob.y = sg * vb.y - acc1[u].y;
                ob.z = sg * vb.z - acc1[u].z; ob.w = sg * vb.w - acc1[u].w;
                *pa = oa; *pb = ob;
            }
        }
        __syncthreads();
    }
    float sg = sigma;

    // exact initial column norms^2 into colv (tracked incrementally during sweeps)
    {
        int c = tid >> 2, part = tid & 3;
        const float4* col = (const float4*)B + c * ESTR4 + part * 12;
        float s = 0.0f;
        #pragma unroll
        for (int u = 0; u < 12; ++u) {
            float4 v = col[u];
            s += v.x * v.x + v.y * v.y + v.z * v.z + v.w * v.w;
        }
        s += __shfl_xor(s, 1); s += __shfl_xor(s, 2);
        if (part == 0) colv[c] = s;
    }
    __syncthreads();

    const float tol2 = 2.5e-11f;   // (5e-6 rel)^2, R1/R2-validated numerics
    const int team16 = tid >> 4, lane16 = tid & 15;
    const int team8 = tid >> 3, lane8 = tid & 7;

    for (int sweep = 0; sweep < nsweep; ++sweep) {
        // ---- 95 super-rounds over 96 super-players (2 cols each) ----
        int p, q;
        if (team16 == 0) { p = 95; q = 0; }
        else             { p = team16; q = 95 - team16; }
        for (int r = 0; r < 95; ++r) {
            const int P0 = 2 * p, P1 = P0 + 1, Q0 = 2 * q, Q1 = Q0 + 1;
            float4* ap0 = B4 + P0 * ESTR4 + lane16;
            float4* ap1 = B4 + P1 * ESTR4 + lane16;
            float4* aq0 = B4 + Q0 * ESTR4 + lane16;
            float4* aq1 = B4 + Q1 * ESTR4 + lane16;
            float4 xp0[3], xp1[3], xq0[3], xq1[3];
            #pragma unroll
            for (int u = 0; u < 3; ++u) {
                xp0[u] = ap0[16 * u]; xp1[u] = ap1[16 * u];
                xq0[u] = aq0[16 * u]; xq1[u] = aq1[16 * u];
            }
            float np0 = colv[P0], np1 = colv[P1], nq0 = colv[Q0], nq1 = colv[Q1];
            bool w0 = false, w1 = false, w2 = false, w3 = false;

            // phase A: (P0,Q0) and (P1,Q1) — disjoint
            float dA0 = 0.f, dA1 = 0.f;
            #pragma unroll
            for (int u = 0; u < 3; ++u) {
                dA0 += xp0[u].x * xq0[u].x + xp0[u].y * xq0[u].y + xp0[u].z * xq0[u].z + xp0[u].w * xq0[u].w;
                dA1 += xp1[u].x * xq1[u].x + xp1[u].y * xq1[u].y + xp1[u].z * xq1[u].z + xp1[u].w * xq1[u].w;
            }
            dA0 = rsum16(dA0); dA1 = rsum16(dA1);
            if (dA0 * dA0 > tol2 * np0 * nq0) {
                float zeta = (nq0 - np0) / (2.0f * dA0);
                float t = copysignf(1.0f, zeta) / (fabsf(zeta) + sqrtf(1.0f + zeta * zeta));
                float cc = 1.0f / sqrtf(1.0f + t * t), ss = t * cc;
                #pragma unroll
                for (int u = 0; u < 3; ++u) {
                    float4 a = xp0[u], b = xq0[u];
                    xp0[u].x = cc * a.x - ss * b.x; xq0[u].x = ss * a.x + cc * b.x;
                    xp0[u].y = cc * a.y - ss * b.y; xq0[u].y = ss * a.y + cc * b.y;
                    xp0[u].z = cc * a.z - ss * b.z; xq0[u].z = ss * a.z + cc * b.z;
                    xp0[u].w = cc * a.w - ss * b.w; xq0[u].w = ss * a.w + cc * b.w;
                }
                float del = t * dA0; np0 -= del; nq0 += del;
                w0 = w2 = true;
            }
            if (dA1 * dA1 > tol2 * np1 * nq1) {
                float zeta = (nq1 - np1) / (2.0f * dA1);
                float t = copysignf(1.0f, zeta) / (fabsf(zeta) + sqrtf(1.0f + zeta * zeta));
                float cc = 1.0f / sqrtf(1.0f + t * t), ss = t * cc;
                #pragma unroll
                for (int u = 0; u < 3; ++u) {
                    float4 a = xp1[u], b = xq1[u];
                    xp1[u].x = cc * a.x - ss * b.x; xq1[u].x = ss * a.x + cc * b.x;
                    xp1[u].y = cc * a.y - ss * b.y; xq1[u].y = ss * a.y + cc * b.y;
                    xp1[u].z = cc * a.z - ss * b.z; xq1[u].z = ss * a.z + cc * b.z;
                    xp1[u].w = cc * a.w - ss * b.w; xq1[u].w = ss * a.w + cc * b.w;
                }
                float del = t * dA1; np1 -= del; nq1 += del;
                w1 = w3 = true;
            }

            // phase B: (P0,Q1) and (P1,Q0) — disjoint, after phase A
            float dB0 = 0.f, dB1 = 0.f;
            #pragma unroll
            for (int u = 0; u < 3; ++u) {
                dB0 += xp0[u].x * xq1[u].x + xp0[u].y * xq1[u].y + xp0[u].z * xq1[u].z + xp0[u].w * xq1[u].w;
                dB1 += xp1[u].x * xq0[u].x + xp1[u].y * xq0[u].y + xp1[u].z * xq0[u].z + xp1[u].w * xq0[u].w;
            }
            dB0 = rsum16(dB0); dB1 = rsum16(dB1);
            if (dB0 * dB0 > tol2 * np0 * nq1) {
                float zeta = (nq1 - np0) / (2.0f * dB0);
                float t = copysignf(1.0f, zeta) / (fabsf(zeta) + sqrtf(1.0f + zeta * zeta));
                float cc = 1.0f / sqrtf(1.0f + t * t), ss = t * cc;
                #pragma unroll
                for (int u = 0; u < 3; ++u) {
                    float4 a = xp0[u], b = xq1[u];
                    xp0[u].x = cc * a.x - ss * b.x; xq1[u].x = ss * a.x + cc * b.x;
                    xp0[u].y = cc * a.y - ss * b.y; xq1[u].y = ss * a.y + cc * b.y;
                    xp0[u].z = cc * a.z - ss * b.z; xq1[u].z = ss * a.z + cc * b.z;
                    xp0[u].w = cc * a.w - ss * b.w; xq1[u].w = ss * a.w + cc * b.w;
                }
                float del = t * dB0; np0 -= del; nq1 += del;
                w0 = w3 = true;
            }
            if (dB1 * dB1 > tol2 * np1 * nq0) {
                float zeta = (nq0 - np1) / (2.0f * dB1);
                float t = copysignf(1.0f, zeta) / (fabsf(zeta) + sqrtf(1.0f + zeta * zeta));
                float cc = 1.0f / sqrtf(1.0f + t * t), ss = t * cc;
                #pragma unroll
                for (int u = 0; u < 3; ++u) {
                    float4 a = xp1[u], b = xq0[u];
                    xp1[u].x = cc * a.x - ss * b.x; xq0[u].x = ss * a.x + cc * b.x;
                    xp1[u].y = cc * a.y - ss * b.y; xq0[u].y = ss * a.y + cc * b.y;
                    xp1[u].z = cc * a.z - ss * b.z; xq0[u].z = ss * a.z + cc * b.z;
                    xp1[u].w = cc * a.w - ss * b.w; xq0[u].w = ss * a.w + cc * b.w;
                }
                float del = t * dB1; np1 -= del; nq0 += del;
                w1 = w2 = true;
            }

            if (w0) { ap0[0] = xp0[0]; ap0[16] = xp0[1]; ap0[32] = xp0[2]; }
            if (w1) { ap1[0] = xp1[0]; ap1[16] = xp1[1]; ap1[32] = xp1[2]; }
            if (w2) { aq0[0] = xq0[0]; aq0[16] = xq0[1]; aq0[32] = xq0[2]; }
            if (w3) { aq1[0] = xq1[0]; aq1[16] = xq1[1]; aq1[32] = xq1[2]; }
            if (lane16 == 0) {
                colv[P0] = np0; colv[P1] = np1; colv[Q0] = nq0; colv[Q1] = nq1;
            }
            __syncthreads();
            if (team16 != 0) p = (p == 94) ? 0 : p + 1;
            q = (q == 94) ? 0 : q + 1;
        }

        // ---- internal-pair round: (2k, 2k+1), 96 teams of 8 lanes ----
        {
            const int c0 = 2 * team8, c1 = c0 + 1;
            float4* a0 = B4 + c0 * ESTR4 + lane8;
            float4* a1 = B4 + c1 * ESTR4 + lane8;
            float4 x0[6], x1[6];
            #pragma unroll
            for (int u = 0; u < 6; ++u) { x0[u] = a0[8 * u]; x1[u] = a1[8 * u]; }
            float n0 = colv[c0], n1 = colv[c1];
            float d = 0.f;
            #pragma unroll
            for (int u = 0; u < 6; ++u)
                d += x0[u].x * x1[u].x + x0[u].y * x1[u].y + x0[u].z * x1[u].z + x0[u].w * x1[u].w;
            d = rsum8(d);
            if (d * d > tol2 * n0 * n1) {
                float zeta = (n1 - n0) / (2.0f * d);
                float t = copysignf(1.0f, zeta) / (fabsf(zeta) + sqrtf(1.0f + zeta * zeta));
                float cc = 1.0f / sqrtf(1.0f + t * t), ss = t * cc;
                #pragma unroll
                for (int u = 0; u < 6; ++u) {
                    float4 a = x0[u], b = x1[u], na, nb;
                    na.x = cc * a.x - ss * b.x; nb.x = ss * a.x + cc * b.x;
                    na.y = cc * a.y - ss * b.y; nb.y = ss * a.y + cc * b.y;
                    na.z = cc * a.z - ss * b.z; nb.z = ss * a.z + cc * b.z;
                    na.w = cc * a.w - ss * b.w; nb.w = ss * a.w + cc * b.w;
                    a0[8 * u] = na; a1[8 * u] = nb;
                }
                float del = t * d;
                if (lane8 == 0) { colv[c0] = n0 - del; colv[c1] = n1 + del; }
            }
            __syncthreads();
        }
    }

    // exact column norms^2
    {
        int c = tid >> 2, part = tid & 3;
        const float4* col = (const float4*)B + c * ESTR4 + part * 12;
        float s = 0.0f;
        #pragma unroll
        for (int u = 0; u < 12; ++u) {
            float4 v = col[u];
            s += v.x * v.x + v.y * v.y + v.z * v.z + v.w * v.w;
        }
        s += __shfl_xor(s, 1); s += __shfl_xor(s, 2);
        if (part == 0) colv[c] = s;
    }
    __syncthreads();

    if (mode == 0) {
        // occupied = nocc largest norms (= smallest eigenvalues of F)
        int noccm = noccA[mol];
        if (tid < NORB) {
            float nc = colv[tid];
            int rank = 0;
            for (int j2 = 0; j2 < NORB; ++j2) {
                float nj = colv[j2];
                rank += (nj > nc) || (nj == nc && j2 < tid);
            }
            slot[tid] = rank;
            colv2[tid] = rsqrtf(nc);     // 1/||b||
        }
        __syncthreads();
        float* Wm = Wout + (size_t)mol * MATSZ;
        float* Vm = Vout + (size_t)mol * MATSZ;
        for (int i4 = tid; i4 < NORB * 48; i4 += EIG_T) {
            int c = i4 / 48, r4 = i4 % 48;
            float inv = colv2[c];
            float4 v = B4[c * ESTR4 + r4];
            float4 nv;
            nv.x = v.x * inv; nv.y = v.y * inv; nv.z = v.z * inv; nv.w = v.w * inv;
            ((float4*)Vm)[i4] = nv;      // full basis for next warm start
            int sl = slot[c];
            if (sl < noccm) {
                float4 o;
                o.x = nv.x * 1.41421356f; o.y = nv.y * 1.41421356f;
                o.z = nv.z * 1.41421356f; o.w = nv.w * 1.41421356f;
                ((float4*)Wm)[sl * 48 + r4] = o;
            }
        }
    } else {
        // eigenvalues ascending
        if (tid < NORB) colv2[tid] = sg - sqrtf(colv[tid]);
        __syncthreads();
        if (tid < NORB) {
            float ec = colv2[tid];
            int rank = 0;
            for (int j2 = 0; j2 < NORB; ++j2) {
                float ej = colv2[j2];
                rank += (ej < ec) || (ej == ec && j2 < tid);
            }
            eout[mol * NORB + rank] = ec;
        }
    }
}

// ---------------- Pnew = W^T W, mix, err ----------------
__global__ void __launch_bounds__(256)
pmix_kernel(const float* __restrict__ W, const int* __restrict__ noccA,
            float* __restrict__ P, unsigned int* __restrict__ err, int last)
{
    int mol = blockIdx.x / 36;
    int tile = blockIdx.x % 36;
    int i0 = (tile / 6) * 32, j0 = (tile % 6) * 32;
    int K = noccA[mol];
    const float* Wm = W + (size_t)mol * MATSZ;
    __shared__ float As[32][33];
    __shared__ float Bs[32][33];
    int t = threadIdx.x;
    int ty = t >> 4, tx = t & 15;
    float acc00 = 0.f, acc01 = 0.f, acc10 = 0.f, acc11 = 0.f;
    for (int k0 = 0; k0 < K; k0 += 32) {
        for (int l = t; l < 1024; l += 256) {
            int k = l >> 5, idx = l & 31;
            bool ok = (k0 + k) < K;
            As[k][idx] = ok ? Wm[(k0 + k) * NORB + i0 + idx] : 0.0f;
            Bs[k][idx] = ok ? Wm[(k0 + k) * NORB + j0 + idx] : 0.0f;
        }
        __syncthreads();
        #pragma unroll 8
        for (int k = 0; k < 32; ++k) {
            float a0 = As[k][2 * ty], a1 = As[k][2 * ty + 1];
            float b0 = Bs[k][2 * tx], b1 = Bs[k][2 * tx + 1];
            acc00 += a0 * b0; acc01 += a0 * b1; acc10 += a1 * b0; acc11 += a1 * b1;
        }
        __syncthreads();
    }
    float* Pm = P + (size_t)mol * MATSZ;
    float lmax = 0.0f;
    int ib = i0 + 2 * ty, jb = j0 + 2 * tx;
    {
        float po, pn;
        po = Pm[ib * NORB + jb];           pn = acc00; lmax = fmaxf(lmax, fabsf(pn - po)); Pm[ib * NORB + jb] = 0.5f * (po + pn);
        po = Pm[ib * NORB + jb + 1];       pn = acc01; lmax = fmaxf(lmax, fabsf(pn - po)); Pm[ib * NORB + jb + 1] = 0.5f * (po + pn);
        po = Pm[(ib + 1) * NORB + jb];     pn = acc10; lmax = fmaxf(lmax, fabsf(pn - po)); Pm[(ib + 1) * NORB + jb] = 0.5f * (po + pn);
        po = Pm[(ib + 1) * NORB + jb + 1]; pn = acc11; lmax = fmaxf(lmax, fabsf(pn - po)); Pm[(ib + 1) * NORB + jb + 1] = 0.5f * (po + pn);
    }
    if (last) {
        #pragma unroll
        for (int o = 32; o >= 1; o >>= 1) lmax = fmaxf(lmax, __shfl_xor(lmax, o));
        __shared__ float wm4[4];
        if ((t & 63) == 0) wm4[t >> 6] = lmax;
        __syncthreads();
        if (t == 0) {
            float m = fmaxf(fmaxf(wm4[0], wm4[1]), fmaxf(wm4[2], wm4[3]));
            atomicMax(err + mol, __float_as_uint(m));
        }
    }
}

// ---------------- charge + notconverged ----------------
__global__ void finish_kernel(const int* __restrict__ Z, const float* __restrict__ P,
    const float* __restrict__ errf, float* __restrict__ chg, float* __restrict__ ncv)
{
    int a = blockIdx.x * blockDim.x + threadIdx.x;
    if (a < NATOMS) {
        int mol = a / MOLS, ai = a % MOLS;
        const float* Pm = P + (size_t)mol * MATSZ;
        float tr = 0.0f;
        #pragma unroll
        for (int p = 0; p < 4; ++p) tr += Pm[(4 * ai + p) * NORB + 4 * ai + p];
        chg[a] = (float)(Z[a] - 2) - tr;
    }
    if (a < NMOL) ncv[a] = (errf[a] > 1e-6f) ? 1.0f : 0.0f;
}

extern "C" void kernel_launch(void* const* d_in, const int* in_sizes, int n_in,
                              void* d_out, int out_size, void* d_ws, size_t ws_size,
                              hipStream_t stream)
{
    (void)in_sizes; (void)n_in; (void)out_size; (void)ws_size;

    const int*   nocc   = (const int*)d_in[3];
    const int*   Z      = (const int*)d_in[4];
    const int*   idxi   = (const int*)d_in[9];
    const int*   idxj   = (const int*)d_in[10];
    const float* xij    = (const float*)d_in[13];
    const float* rij    = (const float*)d_in[14];
    const float* zeta_s = (const float*)d_in[15];
    const float* zeta_p = (const float*)d_in[16];
    const float* U_ss   = (const float*)d_in[17];
    const float* U_pp   = (const float*)d_in[18];
    const float* g_ss   = (const float*)d_in[19];
    const float* g_sp   = (const float*)d_in[20];
    const float* g_pp   = (const float*)d_in[21];
    const float* g_p2   = (const float*)d_in[22];
    const float* h_sp   = (const float*)d_in[23];
    const float* beta_s = (const float*)d_in[24];
    const float* beta_p = (const float*)d_in[25];

    float* out     = (float*)d_out;
    float* F_out   = out + F_OFF;
    float* e_out   = out + E_OFF;
    float* P_out   = out + P_OFF;
    float* H_out   = out + H_OFF;
    float* w_out   = out + WMAT_OFF;
    float* chg_out = out + CHG_OFF;
    float* ncv_out = out + NCV_OFF;

    // V basis (37.75MB) lives in the w output region (115.5MB) during SCF;
    // wout_kernel runs LAST to restore the correct w contents.
    float* Vbuf = w_out;

    char* wsb = (char*)d_ws;
    float* Wocc = (float*)wsb;                                  // 37,748,736 B
    float* wss  = (float*)(wsb + 37748736);                     //  1,155,072 B
    float* Ptot = (float*)(wsb + 37748736 + 1155072);           //     49,152 B
    unsigned int* err = (unsigned int*)(wsb + 37748736 + 1155072 + 49152);

    hipMemsetAsync(err, 0, NMOL * sizeof(unsigned int), stream);

    hipFuncSetAttribute(reinterpret_cast<const void*>(eigh_kernel),
                        hipFuncAttributeMaxDynamicSharedMemorySize, EIG_LDS);

    pair_kernel<<<NPAIR / 256, 256, 0, stream>>>(idxi, idxj, xij, rij, zeta_s, zeta_p,
                                                 g_ss, beta_s, beta_p, wss, H_out);
    atom_kernel<<<NATOMS / 256, 256, 0, stream>>>(Z, U_ss, U_pp, wss, H_out);
    pinit_kernel<<<(NMOL * MATSZ) / 256, 256, 0, stream>>>(Z, P_out);

    // uniform sweep schedule (R2-equivalent): fixed-8-iteration SCF amplifies
    // early-iteration solver error, so every warm iteration gets the same budget.
    const int sweeps[9] = {14, 8, 8, 8, 8, 8, 8, 8, 6};

    for (int it = 0; it < 9; ++it) {
        ptot_kernel<<<NATOMS / 256, 256, 0, stream>>>(P_out, Ptot);
        fockdiag_kernel<<<NATOMS / 256, 256, 0, stream>>>(P_out, H_out, F_out, Ptot, wss,
                                                          g_ss, g_sp, g_pp, g_p2, h_sp);
        fockoff_kernel<<<NPAIR / 256, 256, 0, stream>>>(idxi, idxj, P_out, H_out, F_out, wss);
        if (it < 8) {
            eigh_kernel<<<NMOL, EIG_T, EIG_LDS, stream>>>(F_out, nocc, Vbuf, Vbuf,
                                                          Wocc, e_out, 0, it > 0 ? 1 : 0,
                                                          sweeps[it]);
            pmix_kernel<<<NMOL * 36, 256, 0, stream>>>(Wocc, nocc, P_out, err, (it == 7) ? 1 : 0);
        } else {
            eigh_kernel<<<NMOL, EIG_T, EIG_LDS, stream>>>(F_out, nocc, Vbuf, Vbuf,
                                                          Wocc, e_out, 1, 1, sweeps[8]);
        }
    }
    finish_kernel<<<NATOMS / 256, 256, 0, stream>>>(Z, P_out, (const float*)err, chg_out, ncv_out);
    wout_kernel<<<(NPAIR * 100) / 256, 256, 0, stream>>>(wss, w_out);
}

// Round 7
// 41986.368 us; speedup vs baseline: 2.1217x; 1.3178x over previous
//
#include <hip/hip_runtime.h>

#define NMOL 256
#define MOLS 48
#define NATOMS 12288           // NMOL*MOLS
#define NORB 192               // 4*MOLS
#define PPM 1128               // pairs per molecule = 48*47/2
#define NPAIR 288768           // NMOL*PPM
#define MATSZ 36864            // NORB*NORB
#define EVC 27.21f

// output offsets (floats)
#define F_OFF   0
#define E_OFF   9437184
#define P_OFF   9486336
#define H_OFF   18923520
#define WMAT_OFF 28360704
#define CHG_OFF 57237504
#define NCV_OFF 57249792

__device__ __forceinline__ int pairoff(int i, int j) {
    return 47 * i - (i * (i - 1)) / 2 + (j - i - 1);
}

// ---------------- per-pair: w_ss + Hcore off-diagonal blocks ----------------
__global__ void pair_kernel(
    const int* __restrict__ idxi, const int* __restrict__ idxj,
    const float* __restrict__ xij, const float* __restrict__ rij,
    const float* __restrict__ zeta_s, const float* __restrict__ zeta_p,
    const float* __restrict__ g_ss,
    const float* __restrict__ beta_s, const float* __restrict__ beta_p,
    float* __restrict__ wss, float* __restrict__ H)
{
    int pp = blockIdx.x * blockDim.x + threadIdx.x;
    if (pp >= NPAIR) return;
    int i = idxi[pp], j = idxj[pp];
    float r = rij[pp];
    float rho = 7.0f / g_ss[i] + 7.0f / g_ss[j];
    float base = 1.0f / sqrtf(r * r + rho * rho);
    float wv = EVC * base;
    wss[pp] = wv;

    float x[3] = { xij[pp * 3 + 0], xij[pp * 3 + 1], xij[pp * 3 + 2] };
    float zsi = zeta_s[i], zpi = zeta_p[i], zsj = zeta_s[j], zpj = zeta_p[j];
    float e_ss = expf(-0.5f * (zsi + zsj) * r);
    float e_sp = expf(-0.5f * (zsi + zpj) * r);
    float e_ps = expf(-0.5f * (zpi + zsj) * r);
    float e_pp = expf(-0.5f * (zpi + zpj) * r);

    float S[4][4];
    S[0][0] = e_ss;
    #pragma unroll
    for (int k = 0; k < 3; ++k) {
        S[0][1 + k] = x[k] * e_sp;
        S[1 + k][0] = -x[k] * e_ps;
        #pragma unroll
        for (int l = 0; l < 3; ++l)
            S[1 + k][1 + l] = ((k == l ? 1.0f : 0.0f) - x[k] * x[l]) * e_pp;
    }
    float boi[4] = { beta_s[i], beta_p[i], beta_p[i], beta_p[i] };
    float boj[4] = { beta_s[j], beta_p[j], beta_p[j], beta_p[j] };

    int mol = i / MOLS, ai = i % MOLS, aj = j % MOLS;
    float* Hm = H + (size_t)mol * MATSZ;
    #pragma unroll
    for (int p = 0; p < 4; ++p)
        #pragma unroll
        for (int q = 0; q < 4; ++q) {
            float v = 0.5f * (boi[p] + boj[q]) * S[p][q];
            Hm[(4 * ai + p) * NORB + 4 * aj + q] = v;
            Hm[(4 * aj + q) * NORB + 4 * ai + p] = v;
        }
}

// ---------------- w output (coalesced) ----------------
__global__ void wout_kernel(const float* __restrict__ wss, float* __restrict__ w_out)
{
    int idx = blockIdx.x * blockDim.x + threadIdx.x;
    if (idx >= NPAIR * 100) return;
    int pp = idx / 100, ab = idx % 100;
    int a = ab / 10, b = ab % 10;
    w_out[idx] = wss[pp] * (1.0f + 0.05f * (float)a) * (1.0f + 0.05f * (float)b);
}

// ---------------- per-atom: vatt gather + Hcore diagonal blocks ----------------
__global__ void atom_kernel(const int* __restrict__ Z,
    const float* __restrict__ U_ss, const float* __restrict__ U_pp,
    const float* __restrict__ wss, float* __restrict__ H)
{
    int a = blockIdx.x * blockDim.x + threadIdx.x;
    if (a >= NATOMS) return;
    int mol = a / MOLS, ai = a % MOLS;
    const float* wm = wss + mol * PPM;
    float vatt = 0.0f;
    for (int j = 0; j < MOLS; ++j) {
        if (j == ai) continue;
        int i_ = ai < j ? ai : j;
        int j_ = ai < j ? j : ai;
        float torej = (float)(Z[mol * MOLS + j] - 2);
        vatt -= torej * wm[pairoff(i_, j_)];
    }
    float u0 = U_ss[a], u1 = U_pp[a];
    float* Hm = H + (size_t)mol * MATSZ;
    #pragma unroll
    for (int p = 0; p < 4; ++p)
        #pragma unroll
        for (int q = 0; q < 4; ++q)
            Hm[(4 * ai + p) * NORB + 4 * ai + q] =
                (p == q) ? ((p == 0 ? u0 : u1) + vatt) : 0.0f;
}

// ---------------- initial density ----------------
__global__ void pinit_kernel(const int* __restrict__ Z, float* __restrict__ P)
{
    int idx = blockIdx.x * blockDim.x + threadIdx.x;
    if (idx >= NMOL * MATSZ) return;
    int mol = idx / MATSZ, rem = idx % MATSZ;
    int r = rem / NORB, c = rem % NORB;
    float v = 0.0f;
    if (r == c) v = (float)(Z[mol * MOLS + r / 4] - 2) * 0.25f;
    P[idx] = v;
}

// ---------------- Ptot (trace of diagonal density block) ----------------
__global__ void ptot_kernel(const float* __restrict__ P, float* __restrict__ Ptot)
{
    int a = blockIdx.x * blockDim.x + threadIdx.x;
    if (a >= NATOMS) return;
    int mol = a / MOLS, ai = a % MOLS;
    const float* Pm = P + (size_t)mol * MATSZ;
    float t = 0.0f;
    #pragma unroll
    for (int p = 0; p < 4; ++p) t += Pm[(4 * ai + p) * NORB + 4 * ai + p];
    Ptot[a] = t;
}

// ---------------- Fock diagonal blocks ----------------
__global__ void fockdiag_kernel(
    const float* __restrict__ P, const float* __restrict__ H, float* __restrict__ F,
    const float* __restrict__ Ptot, const float* __restrict__ wss,
    const float* __restrict__ g_ss, const float* __restrict__ g_sp,
    const float* __restrict__ g_pp, const float* __restrict__ g_p2,
    const float* __restrict__ h_sp)
{
    int a = blockIdx.x * blockDim.x + threadIdx.x;
    if (a >= NATOMS) return;
    int mol = a / MOLS, ai = a % MOLS;
    const float* wm = wss + mol * PPM;
    const float* ptm = Ptot + mol * MOLS;
    float vc = 0.0f;
    for (int j = 0; j < MOLS; ++j) {
        if (j == ai) continue;
        int i_ = ai < j ? ai : j;
        int j_ = ai < j ? j : ai;
        vc += wm[pairoff(i_, j_)] * ptm[j];
    }
    const float* Pm = P + (size_t)mol * MATSZ;
    float Pd[4][4];
    #pragma unroll
    for (int p = 0; p < 4; ++p)
        #pragma unroll
        for (int q = 0; q < 4; ++q)
            Pd[p][q] = Pm[(4 * ai + p) * NORB + 4 * ai + q];

    float Pss = Pd[0][0];
    float Pp0 = Pd[1][1], Pp1 = Pd[2][2], Pp2 = Pd[3][3];
    float Ppp = Pp0 + Pp1 + Pp2;
    float gss = g_ss[a], gsp = g_sp[a], gpp = g_pp[a], gp2 = g_p2[a], hsp = h_sp[a];
    float csp = 1.5f * hsp - 0.5f * gsp;
    float gsp_h = gsp - 0.5f * hsp;
    float fss = 0.5f * Pss * gss + Ppp * gsp_h;
    float cp = 1.25f * gp2 - 0.25f * gpp;
    float fpp0 = Pss * gsp_h + 0.5f * Pp0 * gpp + (Ppp - Pp0) * cp;
    float fpp1 = Pss * gsp_h + 0.5f * Pp1 * gpp + (Ppp - Pp1) * cp;
    float fpp2 = Pss * gsp_h + 0.5f * Pp2 * gpp + (Ppp - Pp2) * cp;
    float coff = 0.75f * gpp - 1.25f * gp2;

    float Fd[4][4];
    Fd[0][0] = fss + vc;
    Fd[1][1] = fpp0 + vc; Fd[2][2] = fpp1 + vc; Fd[3][3] = fpp2 + vc;
    #pragma unroll
    for (int k = 0; k < 3; ++k) {
        Fd[0][1 + k] = Pd[0][1 + k] * csp;
        Fd[1 + k][0] = Pd[1 + k][0] * csp;
    }
    Fd[1][2] = coff * Pd[1][2]; Fd[1][3] = coff * Pd[1][3];
    Fd[2][1] = coff * Pd[2][1]; Fd[2][3] = coff * Pd[2][3];
    Fd[3][1] = coff * Pd[3][1]; Fd[3][2] = coff * Pd[3][2];

    const float* Hm = H + (size_t)mol * MATSZ;
    float* Fm = F + (size_t)mol * MATSZ;
    #pragma unroll
    for (int p = 0; p < 4; ++p)
        #pragma unroll
        for (int q = 0; q < 4; ++q) {
            int ix = (4 * ai + p) * NORB + 4 * ai + q;
            Fm[ix] = Hm[ix] + Fd[p][q];
        }
}

// ---------------- Fock off-diagonal blocks ----------------
__global__ void fockoff_kernel(const int* __restrict__ idxi, const int* __restrict__ idxj,
    const float* __restrict__ P, const float* __restrict__ H, float* __restrict__ F,
    const float* __restrict__ wss)
{
    int pp = blockIdx.x * blockDim.x + threadIdx.x;
    if (pp >= NPAIR) return;
    int i = idxi[pp], j = idxj[pp];
    int mol = i / MOLS, ai = i % MOLS, aj = j % MOLS;
    float wv = wss[pp];
    const float* Pm = P + (size_t)mol * MATSZ;
    const float* Hm = H + (size_t)mol * MATSZ;
    float* Fm = F + (size_t)mol * MATSZ;
    #pragma unroll
    for (int p = 0; p < 4; ++p)
        #pragma unroll
        for (int q = 0; q < 4; ++q) {
            int ij = (4 * ai + p) * NORB + 4 * aj + q;
            int ji = (4 * aj + q) * NORB + 4 * ai + p;
            float f = -0.5f * wv * Pm[ij];
            Fm[ij] = Hm[ij] + f;
            Fm[ji] = Hm[ji] + f;
        }
}

// ---------------- batched eigensolver: one-sided Jacobi on sigma*I - F ----------------
// G=4 super-players: 48 players x 4 cols; 24 teams x 16 lanes (384 threads).
// Sweep = 47 cross rounds (16 pairs/match, 4 register-local phases) + 1 intra round
// (6 pairs/player) = 48 barriers (vs 96 in G=2, 191 scalar). Per-pair LDS traffic
// halved vs G=2. Same rotation math / incremental norms / tol2 write-skip as R6.
#define EIG_T 384
#define ESTR 196     // padded column stride in floats
#define ESTR4 49     // in float4
#define EIG_LDS (( (ESTR*NORB) + 2*NORB ) * 4 + NORB * 4)

__device__ __forceinline__ float rsum16(float v) {
    v += __shfl_xor(v, 1); v += __shfl_xor(v, 2);
    v += __shfl_xor(v, 4); v += __shfl_xor(v, 8);
    return v;
}

__device__ __forceinline__ float dot3(const float4* a, const float4* b) {
    float t = 0.0f;
    #pragma unroll
    for (int u = 0; u < 3; ++u)
        t += a[u].x * b[u].x + a[u].y * b[u].y + a[u].z * b[u].z + a[u].w * b[u].w;
    return t;
}

__device__ __forceinline__ void rot3(float4* a, float4* b, float cc, float ss) {
    #pragma unroll
    for (int u = 0; u < 3; ++u) {
        float4 av = a[u], bv = b[u];
        a[u].x = cc * av.x - ss * bv.x;  b[u].x = ss * av.x + cc * bv.x;
        a[u].y = cc * av.y - ss * bv.y;  b[u].y = ss * av.y + cc * bv.y;
        a[u].z = cc * av.z - ss * bv.z;  b[u].z = ss * av.z + cc * bv.z;
        a[u].w = cc * av.w - ss * bv.w;  b[u].w = ss * av.w + cc * bv.w;
    }
}

// rotate pair (a,b) if off-diag above threshold; exact incremental norm update
__device__ __forceinline__ bool jrot(float d, float& na, float& nb,
                                     float4* a, float4* b, float tol2) {
    if (d * d > tol2 * na * nb) {
        float zeta = (nb - na) / (2.0f * d);
        float t = copysignf(1.0f, zeta) / (fabsf(zeta) + sqrtf(1.0f + zeta * zeta));
        float cc = 1.0f / sqrtf(1.0f + t * t), ss = t * cc;
        rot3(a, b, cc, ss);
        float del = t * d; na -= del; nb += del;
        return true;
    }
    return false;
}

__global__ void __launch_bounds__(EIG_T)
eigh_kernel(const float* __restrict__ Fg, const int* __restrict__ noccA,
            const float* __restrict__ Vin, float* __restrict__ Vout,
            float* __restrict__ Wout, float* __restrict__ eout,
            int mode, int warm, int nsweep)
{
    extern __shared__ float sm[];
    float* B = sm;                          // ESTR*NORB
    float* colv = sm + ESTR * NORB;         // NORB (norms^2, tracked)
    float* colv2 = colv + NORB;             // NORB
    int* slot = (int*)(colv2 + NORB);       // NORB
    __shared__ float sigma;

    const int mol = blockIdx.x;
    const int tid = threadIdx.x;
    const float* Fm = Fg + (size_t)mol * MATSZ;
    float4* B4 = (float4*)B;

    if (!warm) {
        // cold: load F into LDS (padded columns; symmetric so col-major == row-major)
        for (int i4 = tid; i4 < NORB * 48; i4 += EIG_T) {
            int c = i4 / 48, r4 = i4 % 48;
            B4[c * ESTR4 + r4] = ((const float4*)Fm)[i4];
        }
        __syncthreads();
        // Gershgorin per column from LDS (2 lanes per column)
        {
            int c = tid >> 1, part = tid & 1;
            const float4* col = (const float4*)B + c * ESTR4 + part * 24;
            float s = 0.0f;
            #pragma unroll
            for (int u = 0; u < 24; ++u) {
                float4 v = col[u];
                s += fabsf(v.x) + fabsf(v.y) + fabsf(v.z) + fabsf(v.w);
            }
            s += __shfl_xor(s, 1);
            if (part == 0) { float d = B[c * ESTR + c]; colv[c] = s - fabsf(d) + d; }
        }
        __syncthreads();
        if (tid < 64) {
            float m = -3.4e38f;
            for (int i = tid; i < NORB; i += 64) m = fmaxf(m, colv[i]);
            #pragma unroll
            for (int o = 32; o >= 1; o >>= 1) m = fmaxf(m, __shfl_xor(m, o));
            if (tid == 0) sigma = m + 1.0f + 1e-3f * fabsf(m);
        }
        __syncthreads();
        float sg = sigma;
        // B = sigma*I - F
        for (int i4 = tid; i4 < NORB * 48; i4 += EIG_T) {
            int c = i4 / 48, r4 = i4 % 48;
            float4* pv = B4 + c * ESTR4 + r4;
            float4 v = *pv;
            v.x = -v.x; v.y = -v.y; v.z = -v.z; v.w = -v.w;
            *pv = v;
        }
        __syncthreads();
        if (tid < NORB) B[tid * ESTR + tid] += sg;
        __syncthreads();
    } else {
        // warm: load Vprev into LDS
        for (int i4 = tid; i4 < NORB * 48; i4 += EIG_T) {
            int c = i4 / 48, r4 = i4 % 48;
            B4[c * ESTR4 + r4] = ((const float4*)Vin)[(size_t)mol * (MATSZ / 4) + i4];
        }
        // Gershgorin per column from GLOBAL F (no dependency on V load)
        {
            int c = tid >> 1, part = tid & 1;
            const float4* col = (const float4*)(Fm + c * NORB) + part * 24;
            float s = 0.0f;
            #pragma unroll
            for (int u = 0; u < 24; ++u) {
                float4 v = col[u];
                s += fabsf(v.x) + fabsf(v.y) + fabsf(v.z) + fabsf(v.w);
            }
            s += __shfl_xor(s, 1);
            if (part == 0) { float d = Fm[c * NORB + c]; colv[c] = s - fabsf(d) + d; }
        }
        __syncthreads();
        if (tid < 64) {
            float m = -3.4e38f;
            for (int i = tid; i < NORB; i += 64) m = fmaxf(m, colv[i]);
            #pragma unroll
            for (int o = 32; o >= 1; o >>= 1) m = fmaxf(m, __shfl_xor(m, o));
            if (tid == 0) sigma = m + 1.0f + 1e-3f * fabsf(m);
        }
        __syncthreads();
        float sg = sigma;
        // B[:,j] = sg*V[:,j] - F*V[:,j]; 48 teams of 8 lanes, 2 cols per team,
        // two sequential halves (cols 0..95, 96..191). No hazards: each team only
        // reads/writes its own columns.
        {
            int t8 = tid >> 3, l8 = tid & 7;
            const float4* F4 = (const float4*)Fm;
            #pragma unroll
            for (int half = 0; half < 2; ++half) {
                int j0 = 2 * t8 + 96 * half, j1 = j0 + 1;
                float4 acc0[6], acc1[6];
                #pragma unroll
                for (int u = 0; u < 6; ++u) {
                    acc0[u].x = acc0[u].y = acc0[u].z = acc0[u].w = 0.0f;
                    acc1[u].x = acc1[u].y = acc1[u].z = acc1[u].w = 0.0f;
                }
                for (int k = 0; k < NORB; ++k) {
                    float v0 = B[j0 * ESTR + k];
                    float v1 = B[j1 * ESTR + k];
                    const float4* Fk = F4 + k * 48 + l8;
                    #pragma unroll
                    for (int u = 0; u < 6; ++u) {
                        float4 f = Fk[8 * u];
                        acc0[u].x += f.x * v0; acc0[u].y += f.y * v0;
                        acc0[u].z += f.z * v0; acc0[u].w += f.w * v0;
                        acc1[u].x += f.x * v1; acc1[u].y += f.y * v1;
                        acc1[u].z += f.z * v1; acc1[u].w += f.w * v1;
                    }
                }
                #pragma unroll
                for (int u = 0; u < 6; ++u) {
                    int r4 = l8 + 8 * u;
                    float4* pa = B4 + j0 * ESTR4 + r4;
                    float4* pb = B4 + j1 * ESTR4 + r4;
                    float4 va = *pa, vb = *pb, oa, ob;
                    oa.x = sg * va.x - acc0[u].x; oa.y = sg * va.y - acc0[u].y;
                    oa.z = sg * va.z - acc0[u].z; oa.w = sg * va.w - acc0[u].w;
                    ob.x = sg * vb.x - acc1[u].x; ob.y = sg * vb.y - acc1[u].y;
                    ob.z = sg * vb.z - acc1[u].z; ob.w = sg * vb.w - acc1[u].w;
                    *pa = oa; *pb = ob;
                }
            }
        }
        __syncthreads();
    }
    float sg = sigma;

    // exact initial column norms^2 into colv (tracked incrementally during sweeps)
    {
        int c = tid >> 1, part = tid & 1;
        const float4* col = (const float4*)B + c * ESTR4 + part * 24;
        float s = 0.0f;
        #pragma unroll
        for (int u = 0; u < 24; ++u) {
            float4 v = col[u];
            s += v.x * v.x + v.y * v.y + v.z * v.z + v.w * v.w;
        }
        s += __shfl_xor(s, 1);
        if (part == 0) colv[c] = s;
    }
    __syncthreads();

    const float tol2 = 2.5e-11f;   // (5e-6 rel)^2, R1/R2/R6-validated numerics
    const int team16 = tid >> 4, lane16 = tid & 15;

    for (int sweep = 0; sweep < nsweep; ++sweep) {
        // ---- 47 cross rounds over 48 players (4 cols each) ----
        int p, q;
        if (team16 == 0) { p = 47; q = 0; }
        else             { p = team16; q = 47 - team16; }
        for (int r = 0; r < 47; ++r) {
            float4 xp[4][3], xq[4][3];
            float np[4], nq[4];
            bool wp[4] = {false,false,false,false};
            bool wq[4] = {false,false,false,false};
            #pragma unroll
            for (int i = 0; i < 4; ++i) {
                const float4* ap = B4 + (4 * p + i) * ESTR4 + lane16;
                const float4* aq = B4 + (4 * q + i) * ESTR4 + lane16;
                xp[i][0] = ap[0]; xp[i][1] = ap[16]; xp[i][2] = ap[32];
                xq[i][0] = aq[0]; xq[i][1] = aq[16]; xq[i][2] = aq[32];
                np[i] = colv[4 * p + i]; nq[i] = colv[4 * q + i];
            }
            // 4 phases of 4 disjoint pairs (p_i, q_{(i+s)&3}), register-local
            #pragma unroll
            for (int s = 0; s < 4; ++s) {
                float d[4];
                #pragma unroll
                for (int i = 0; i < 4; ++i)
                    d[i] = dot3(xp[i], xq[(i + s) & 3]);
                #pragma unroll
                for (int i = 0; i < 4; ++i)
                    d[i] = rsum16(d[i]);
                #pragma unroll
                for (int i = 0; i < 4; ++i) {
                    int j = (i + s) & 3;
                    if (jrot(d[i], np[i], nq[j], xp[i], xq[j], tol2)) {
                        wp[i] = true; wq[j] = true;
                    }
                }
            }
            #pragma unroll
            for (int i = 0; i < 4; ++i) {
                if (wp[i]) {
                    float4* ap = B4 + (4 * p + i) * ESTR4 + lane16;
                    ap[0] = xp[i][0]; ap[16] = xp[i][1]; ap[32] = xp[i][2];
                }
                if (wq[i]) {
                    float4* aq = B4 + (4 * q + i) * ESTR4 + lane16;
                    aq[0] = xq[i][0]; aq[16] = xq[i][1]; aq[32] = xq[i][2];
                }
            }
            if (lane16 == 0) {
                #pragma unroll
                for (int i = 0; i < 4; ++i) {
                    colv[4 * p + i] = np[i]; colv[4 * q + i] = nq[i];
                }
            }
            __syncthreads();
            if (team16 != 0) p = (p == 46) ? 0 : p + 1;
            q = (q == 46) ? 0 : q + 1;
        }

        // ---- intra-player round: team handles players 2t, 2t+1 (6 pairs each) ----
        {
            const int plA = 2 * team16, plB = plA + 1;
            float4 xa[4][3], xb[4][3];
            float na[4], nb[4];
            bool wa[4] = {false,false,false,false};
            bool wb[4] = {false,false,false,false};
            #pragma unroll
            for (int i = 0; i < 4; ++i) {
                const float4* aa = B4 + (4 * plA + i) * ESTR4 + lane16;
                const float4* ab = B4 + (4 * plB + i) * ESTR4 + lane16;
                xa[i][0] = aa[0]; xa[i][1] = aa[16]; xa[i][2] = aa[32];
                xb[i][0] = ab[0]; xb[i][1] = ab[16]; xb[i][2] = ab[32];
                na[i] = colv[4 * plA + i]; nb[i] = colv[4 * plB + i];
            }
            // 3 phases: (0,1)(2,3) / (0,2)(1,3) / (0,3)(1,2) for both players
            const int pi0[3] = {0, 0, 0}, pj0[3] = {1, 2, 3};
            const int pi1[3] = {2, 1, 1}, pj1[3] = {3, 3, 2};
            #pragma unroll
            for (int s = 0; s < 3; ++s) {
                int i0 = pi0[s], j0 = pj0[s], i1 = pi1[s], j1 = pj1[s];
                float d0 = dot3(xa[i0], xa[j0]);
                float d1 = dot3(xa[i1], xa[j1]);
                float d2 = dot3(xb[i0], xb[j0]);
                float d3 = dot3(xb[i1], xb[j1]);
                d0 = rsum16(d0); d1 = rsum16(d1); d2 = rsum16(d2); d3 = rsum16(d3);
                if (jrot(d0, na[i0], na[j0], xa[i0], xa[j0], tol2)) { wa[i0] = wa[j0] = true; }
                if (jrot(d1, na[i1], na[j1], xa[i1], xa[j1], tol2)) { wa[i1] = wa[j1] = true; }
                if (jrot(d2, nb[i0], nb[j0], xb[i0], xb[j0], tol2)) { wb[i0] = wb[j0] = true; }
                if (jrot(d3, nb[i1], nb[j1], xb[i1], xb[j1], tol2)) { wb[i1] = wb[j1] = true; }
            }
            #pragma unroll
            for (int i = 0; i < 4; ++i) {
                if (wa[i]) {
                    float4* aa = B4 + (4 * plA + i) * ESTR4 + lane16;
                    aa[0] = xa[i][0]; aa[16] = xa[i][1]; aa[32] = xa[i][2];
                }
                if (wb[i]) {
                    float4* ab = B4 + (4 * plB + i) * ESTR4 + lane16;
                    ab[0] = xb[i][0]; ab[16] = xb[i][1]; ab[32] = xb[i][2];
                }
            }
            if (lane16 == 0) {
                #pragma unroll
                for (int i = 0; i < 4; ++i) {
                    colv[4 * plA + i] = na[i]; colv[4 * plB + i] = nb[i];
                }
            }
            __syncthreads();
        }
    }

    // exact column norms^2
    {
        int c = tid >> 1, part = tid & 1;
        const float4* col = (const float4*)B + c * ESTR4 + part * 24;
        float s = 0.0f;
        #pragma unroll
        for (int u = 0; u < 24; ++u) {
            float4 v = col[u];
            s += v.x * v.x + v.y * v.y + v.z * v.z + v.w * v.w;
        }
        s += __shfl_xor(s, 1);
        if (part == 0) colv[c] = s;
    }
    __syncthreads();

    if (mode == 0) {
        // occupied = nocc largest norms (= smallest eigenvalues of F)
        int noccm = noccA[mol];
        if (tid < NORB) {
            float nc = colv[tid];
            int rank = 0;
            for (int j2 = 0; j2 < NORB; ++j2) {
                float nj = colv[j2];
                rank += (nj > nc) || (nj == nc && j2 < tid);
            }
            slot[tid] = rank;
            colv2[tid] = rsqrtf(nc);     // 1/||b||
        }
        __syncthreads();
        float* Wm = Wout + (size_t)mol * MATSZ;
        float* Vm = Vout + (size_t)mol * MATSZ;
        for (int i4 = tid; i4 < NORB * 48; i4 += EIG_T) {
            int c = i4 / 48, r4 = i4 % 48;
            float inv = colv2[c];
            float4 v = B4[c * ESTR4 + r4];
            float4 nv;
            nv.x = v.x * inv; nv.y = v.y * inv; nv.z = v.z * inv; nv.w = v.w * inv;
            ((float4*)Vm)[i4] = nv;      // full basis for next warm start
            int sl = slot[c];
            if (sl < noccm) {
                float4 o;
                o.x = nv.x * 1.41421356f; o.y = nv.y * 1.41421356f;
                o.z = nv.z * 1.41421356f; o.w = nv.w * 1.41421356f;
                ((float4*)Wm)[sl * 48 + r4] = o;
            }
        }
    } else {
        // eigenvalues ascending
        if (tid < NORB) colv2[tid] = sg - sqrtf(colv[tid]);
        __syncthreads();
        if (tid < NORB) {
            float ec = colv2[tid];
            int rank = 0;
            for (int j2 = 0; j2 < NORB; ++j2) {
                float ej = colv2[j2];
                rank += (ej < ec) || (ej == ec && j2 < tid);
            }
            eout[mol * NORB + rank] = ec;
        }
    }
}

// ---------------- Pnew = W^T W, mix, err ----------------
__global__ void __launch_bounds__(256)
pmix_kernel(const float* __restrict__ W, const int* __restrict__ noccA,
            float* __restrict__ P, unsigned int* __restrict__ err, int last)
{
    int mol = blockIdx.x / 36;
    int tile = blockIdx.x % 36;
    int i0 = (tile / 6) * 32, j0 = (tile % 6) * 32;
    int K = noccA[mol];
    const float* Wm = W + (size_t)mol * MATSZ;
    __shared__ float As[32][33];
    __shared__ float Bs[32][33];
    int t = threadIdx.x;
    int ty = t >> 4, tx = t & 15;
    float acc00 = 0.f, acc01 = 0.f, acc10 = 0.f, acc11 = 0.f;
    for (int k0 = 0; k0 < K; k0 += 32) {
        for (int l = t; l < 1024; l += 256) {
            int k = l >> 5, idx = l & 31;
            bool ok = (k0 + k) < K;
            As[k][idx] = ok ? Wm[(k0 + k) * NORB + i0 + idx] : 0.0f;
            Bs[k][idx] = ok ? Wm[(k0 + k) * NORB + j0 + idx] : 0.0f;
        }
        __syncthreads();
        #pragma unroll 8
        for (int k = 0; k < 32; ++k) {
            float a0 = As[k][2 * ty], a1 = As[k][2 * ty + 1];
            float b0 = Bs[k][2 * tx], b1 = Bs[k][2 * tx + 1];
            acc00 += a0 * b0; acc01 += a0 * b1; acc10 += a1 * b0; acc11 += a1 * b1;
        }
        __syncthreads();
    }
    float* Pm = P + (size_t)mol * MATSZ;
    float lmax = 0.0f;
    int ib = i0 + 2 * ty, jb = j0 + 2 * tx;
    {
        float po, pn;
        po = Pm[ib * NORB + jb];           pn = acc00; lmax = fmaxf(lmax, fabsf(pn - po)); Pm[ib * NORB + jb] = 0.5f * (po + pn);
        po = Pm[ib * NORB + jb + 1];       pn = acc01; lmax = fmaxf(lmax, fabsf(pn - po)); Pm[ib * NORB + jb + 1] = 0.5f * (po + pn);
        po = Pm[(ib + 1) * NORB + jb];     pn = acc10; lmax = fmaxf(lmax, fabsf(pn - po)); Pm[(ib + 1) * NORB + jb] = 0.5f * (po + pn);
        po = Pm[(ib + 1) * NORB + jb + 1]; pn = acc11; lmax = fmaxf(lmax, fabsf(pn - po)); Pm[(ib + 1) * NORB + jb + 1] = 0.5f * (po + pn);
    }
    if (last) {
        #pragma unroll
        for (int o = 32; o >= 1; o >>= 1) lmax = fmaxf(lmax, __shfl_xor(lmax, o));
        __shared__ float wm4[4];
        if ((t & 63) == 0) wm4[t >> 6] = lmax;
        __syncthreads();
        if (t == 0) {
            float m = fmaxf(fmaxf(wm4[0], wm4[1]), fmaxf(wm4[2], wm4[3]));
            atomicMax(err + mol, __float_as_uint(m));
        }
    }
}

// ---------------- charge + notconverged ----------------
__global__ void finish_kernel(const int* __restrict__ Z, const float* __restrict__ P,
    const float* __restrict__ errf, float* __restrict__ chg, float* __restrict__ ncv)
{
    int a = blockIdx.x * blockDim.x + threadIdx.x;
    if (a < NATOMS) {
        int mol = a / MOLS, ai = a % MOLS;
        const float* Pm = P + (size_t)mol * MATSZ;
        float tr = 0.0f;
        #pragma unroll
        for (int p = 0; p < 4; ++p) tr += Pm[(4 * ai + p) * NORB + 4 * ai + p];
        chg[a] = (float)(Z[a] - 2) - tr;
    }
    if (a < NMOL) ncv[a] = (errf[a] > 1e-6f) ? 1.0f : 0.0f;
}

extern "C" void kernel_launch(void* const* d_in, const int* in_sizes, int n_in,
                              void* d_out, int out_size, void* d_ws, size_t ws_size,
                              hipStream_t stream)
{
    (void)in_sizes; (void)n_in; (void)out_size; (void)ws_size;

    const int*   nocc   = (const int*)d_in[3];
    const int*   Z      = (const int*)d_in[4];
    const int*   idxi   = (const int*)d_in[9];
    const int*   idxj   = (const int*)d_in[10];
    const float* xij    = (const float*)d_in[13];
    const float* rij    = (const float*)d_in[14];
    const float* zeta_s = (const float*)d_in[15];
    const float* zeta_p = (const float*)d_in[16];
    const float* U_ss   = (const float*)d_in[17];
    const float* U_pp   = (const float*)d_in[18];
    const float* g_ss   = (const float*)d_in[19];
    const float* g_sp   = (const float*)d_in[20];
    const float* g_pp   = (const float*)d_in[21];
    const float* g_p2   = (const float*)d_in[22];
    const float* h_sp   = (const float*)d_in[23];
    const float* beta_s = (const float*)d_in[24];
    const float* beta_p = (const float*)d_in[25];

    float* out     = (float*)d_out;
    float* F_out   = out + F_OFF;
    float* e_out   = out + E_OFF;
    float* P_out   = out + P_OFF;
    float* H_out   = out + H_OFF;
    float* w_out   = out + WMAT_OFF;
    float* chg_out = out + CHG_OFF;
    float* ncv_out = out + NCV_OFF;

    // V basis (37.75MB) lives in the w output region (115.5MB) during SCF;
    // wout_kernel runs LAST to restore the correct w contents.
    float* Vbuf = w_out;

    char* wsb = (char*)d_ws;
    float* Wocc = (float*)wsb;                                  // 37,748,736 B
    float* wss  = (float*)(wsb + 37748736);                     //  1,155,072 B
    float* Ptot = (float*)(wsb + 37748736 + 1155072);           //     49,152 B
    unsigned int* err = (unsigned int*)(wsb + 37748736 + 1155072 + 49152);

    hipMemsetAsync(err, 0, NMOL * sizeof(unsigned int), stream);

    hipFuncSetAttribute(reinterpret_cast<const void*>(eigh_kernel),
                        hipFuncAttributeMaxDynamicSharedMemorySize, EIG_LDS);

    pair_kernel<<<NPAIR / 256, 256, 0, stream>>>(idxi, idxj, xij, rij, zeta_s, zeta_p,
                                                 g_ss, beta_s, beta_p, wss, H_out);
    atom_kernel<<<NATOMS / 256, 256, 0, stream>>>(Z, U_ss, U_pp, wss, H_out);
    pinit_kernel<<<(NMOL * MATSZ) / 256, 256, 0, stream>>>(Z, P_out);

    // R6-validated uniform schedule (unchanged — one variable per round)
    const int sweeps[9] = {14, 8, 8, 8, 8, 8, 8, 8, 6};

    for (int it = 0; it < 9; ++it) {
        ptot_kernel<<<NATOMS / 256, 256, 0, stream>>>(P_out, Ptot);
        fockdiag_kernel<<<NATOMS / 256, 256, 0, stream>>>(P_out, H_out, F_out, Ptot, wss,
                                                          g_ss, g_sp, g_pp, g_p2, h_sp);
        fockoff_kernel<<<NPAIR / 256, 256, 0, stream>>>(idxi, idxj, P_out, H_out, F_out, wss);
        if (it < 8) {
            eigh_kernel<<<NMOL, EIG_T, EIG_LDS, stream>>>(F_out, nocc, Vbuf, Vbuf,
                                                          Wocc, e_out, 0, it > 0 ? 1 : 0,
                                                          sweeps[it]);
            pmix_kernel<<<NMOL * 36, 256, 0, stream>>>(Wocc, nocc, P_out, err, (it == 7) ? 1 : 0);
        } else {
            eigh_kernel<<<NMOL, EIG_T, EIG_LDS, stream>>>(F_out, nocc, Vbuf, Vbuf,
                                                          Wocc, e_out, 1, 1, sweeps[8]);
        }
    }
    finish_kernel<<<NATOMS / 256, 256, 0, stream>>>(Z, P_out, (const float*)err, chg_out, ncv_out);
    wout_kernel<<<(NPAIR * 100) / 256, 256, 0, stream>>>(wss, w_out);
}